// Round 7
// baseline (5278.816 us; speedup 1.0000x reference)
//
#include <hip/hip_runtime.h>

#define E_TRIP 500000
#define EPAD   500224              // multiple of 256
#define NTILE64 (EPAD/64)          // 7816
#define NN 100000
#define EPSF 1e-5f
#define GRID_MEGA 1024
#define SLOTS 8                    // ceil(NTILE64 / GRID_MEGA)

typedef _Float16 f16;
typedef _Float16 f16x8 __attribute__((ext_vector_type(8)));
typedef float f32x4 __attribute__((ext_vector_type(4)));

// ---------------- prep ----------------
__global__ __launch_bounds__(256) void k_count(const int* __restrict__ ewf,
    const int* __restrict__ exij, const int* __restrict__ exjk,
    unsigned char* __restrict__ biedge, int* __restrict__ sc)
{
  int e = blockIdx.x*256 + threadIdx.x;
  bool active = e < E_TRIP;
  int b = 0;
  if (active) {
    int fij = ewf[exij[e]];
    int fjk = ewf[exjk[e]];
    b = (fij == fjk) ? 0 : 1;
    biedge[e] = (unsigned char)b;
  }
  unsigned long long m0 = __ballot(active && b==0);
  unsigned long long m1 = __ballot(active && b==1);
  int lane = threadIdx.x & 63;
  if (m0 && lane == (__ffsll((long long)m0)-1)) atomicAdd(&sc[0], (int)__popcll(m0));
  if (m1 && lane == (__ffsll((long long)m1)-1)) atomicAdd(&sc[1], (int)__popcll(m1));
}

__global__ void k_scal(int* sc)
{
  int c0 = sc[0], c1 = sc[1];
  int c0p = (c0 + 63) & ~63;
  sc[2] = 0;
  sc[3] = c0p;
  sc[4] = c0;
  sc[5] = c0p;
  sc[6] = c1;
}

__global__ __launch_bounds__(256) void k_partition(const unsigned char* __restrict__ biedge,
    const int* __restrict__ eidx, int* __restrict__ sc,
    int* __restrict__ epos, int* __restrict__ ip, int* __restrict__ jp, int* __restrict__ kp)
{
  int e = blockIdx.x*256 + threadIdx.x;
  bool active = e < E_TRIP;
  int b = active ? (int)biedge[e] : 0;
  unsigned long long m0 = __ballot(active && b==0);
  unsigned long long m1 = __ballot(active && b==1);
  if (active) {
    unsigned long long m = b ? m1 : m0;
    unsigned pre = __builtin_amdgcn_mbcnt_lo((unsigned)m, 0u);
    pre = __builtin_amdgcn_mbcnt_hi((unsigned)(m >> 32), pre);
    int leader = (int)__ffsll((long long)m) - 1;
    int lane = threadIdx.x & 63;
    int base = 0;
    if (lane == leader) base = atomicAdd(&sc[2+b], (int)__popcll(m));
    base = __shfl(base, leader);
    int pos = base + (int)pre;
    epos[pos] = e;
    ip[pos] = eidx[e];
    jp[pos] = eidx[E_TRIP + e];
    kp[pos] = eidx[2*E_TRIP + e];
  }
}

__global__ __launch_bounds__(256) void k_cvt(const float* __restrict__ W0,
    const float* __restrict__ Wr, const float* __restrict__ nf,
    f16* __restrict__ W0h, f16* __restrict__ Wrh, f16* __restrict__ nfh)
{
  int i = blockIdx.x*256 + threadIdx.x;
  if (i < 98304) W0h[i] = (f16)W0[i];
  else if (i < 98304 + 73728) Wrh[i - 98304] = (f16)Wr[i - 98304];
  else { int j = i - 172032; if (j < NN*64) nfh[j] = (f16)nf[j]; }
}

// ---- destination counting sort ----
__global__ __launch_bounds__(256) void k_hist(const int* __restrict__ ip,
    const int* __restrict__ sc, int* __restrict__ cnt)
{
  int p = blockIdx.x*256 + threadIdx.x;
  int c0 = sc[4], c0p = sc[5], c1 = sc[6];
  bool valid = (p < c0) || (p >= c0p && p < c0p + c1);
  if (valid) atomicAdd(&cnt[ip[p]], 1);
}

__global__ __launch_bounds__(512) void k_scan1(const int* __restrict__ cnt,
    int* __restrict__ start, int* __restrict__ btot)
{
  __shared__ int s[512];
  int tid = threadIdx.x;
  int g = blockIdx.x*512 + tid;
  int x = (g < NN) ? cnt[g] : 0;
  s[tid] = x; __syncthreads();
  #pragma unroll
  for (int off = 1; off < 512; off <<= 1) {
    int v = (tid >= off) ? s[tid-off] : 0;
    __syncthreads();
    s[tid] += v;
    __syncthreads();
  }
  if (g < NN) start[g] = s[tid] - x;
  if (tid == 511) btot[blockIdx.x] = s[511];
}

__global__ __launch_bounds__(256) void k_scan2(int* __restrict__ btot)
{
  __shared__ int s[256];
  int tid = threadIdx.x;
  int x = (tid < 196) ? btot[tid] : 0;
  s[tid] = x; __syncthreads();
  #pragma unroll
  for (int off = 1; off < 256; off <<= 1) {
    int v = (tid >= off) ? s[tid-off] : 0;
    __syncthreads();
    s[tid] += v;
    __syncthreads();
  }
  if (tid < 196) btot[tid] = s[tid] - x;
}

__global__ __launch_bounds__(512) void k_scan3(int* __restrict__ start,
    int* __restrict__ cur, const int* __restrict__ btot, const int* __restrict__ sc)
{
  int tid = threadIdx.x;
  int g = blockIdx.x*512 + tid;
  if (g < NN) {
    int v = start[g] + btot[blockIdx.x];
    start[g] = v;
    cur[g] = v;
  }
  if (g == 0) start[NN] = sc[4] + sc[6];
}

__global__ __launch_bounds__(256) void k_place(const int* __restrict__ ip,
    const int* __restrict__ sc, int* __restrict__ cur,
    int* __restrict__ invp, unsigned char* __restrict__ dbr)
{
  int p = blockIdx.x*256 + threadIdx.x;
  int c0 = sc[4], c0p = sc[5], c1 = sc[6];
  bool valid = (p < c0) || (p >= c0p && p < c0p + c1);
  if (valid) {
    int pos = atomicAdd(&cur[ip[p]], 1);
    invp[p] = pos;
    dbr[pos] = (p >= c0p) ? 1 : 0;
  }
}

// ---------------- geo MLP input layer ----------------
__global__ __launch_bounds__(256) void k_geo(
    const float* __restrict__ coords, const float* __restrict__ facex,
    const int* __restrict__ ewf, const int* __restrict__ exij, const int* __restrict__ exjk,
    const float* __restrict__ Wgeo, const float* __restrict__ bgeo,
    const int* __restrict__ sc, const int* __restrict__ epos,
    const int* __restrict__ ip, const int* __restrict__ jp, const int* __restrict__ kp,
    f16* __restrict__ zgeo, float* __restrict__ gstats)
{
  __shared__ f16 lds[256*72];
  __shared__ float sstat[64][2];
  int tid = threadIdx.x;
  int base = blockIdx.x*256;
  int c0 = sc[4], c0p = sc[5], c1 = sc[6];
  if (tid < 128) ((float*)sstat)[tid] = 0.f;
  {
    int p = base + tid;
    bool valid = (p < c0) || (p >= c0p && p < c0p + c1);
    f16* lrow = lds + tid*72;
    if (valid) {
      int e = epos[p];
      int ii = ip[p], jj = jp[p], kk = kp[p];
      float cix = coords[ii*3+0], ciy = coords[ii*3+1], ciz = coords[ii*3+2];
      float cjx = coords[jj*3+0], cjy = coords[jj*3+1], cjz = coords[jj*3+2];
      float ckx = coords[kk*3+0], cky = coords[kk*3+1], ckz = coords[kk*3+2];
      float v1x = cjx-cix, v1y = cjy-ciy, v1z = cjz-ciz;
      float v2x = ckx-cjx, v2y = cky-cjy, v2z = ckz-cjz;
      float dij = sqrtf(v1x*v1x + v1y*v1y + v1z*v1z);
      float djk = sqrtf(v2x*v2x + v2y*v2y + v2z*v2z);
      float cx = v1y*v2z - v1z*v2y;
      float cy = v1z*v2x - v1x*v2z;
      float cz = v1x*v2y - v1y*v2x;
      float theta = atan2f(sqrtf(cx*cx+cy*cy+cz*cz), v1x*v2x+v1y*v2y+v1z*v2z);
      lrow[0]=(f16)dij; lrow[1]=(f16)djk; lrow[2]=(f16)theta; lrow[3]=(f16)0.f;
      lrow[4]=(f16)cjx; lrow[5]=(f16)cjy; lrow[6]=(f16)cjz;
      lrow[7]=(f16)cix; lrow[8]=(f16)ciy; lrow[9]=(f16)ciz;
      int fij = ewf[exij[e]], fjk = ewf[exjk[e]];
      const float* fx1 = facex + (size_t)fij*23;
      const float* fx2 = facex + (size_t)fjk*23;
      for (int c = 0; c < 23; c++) lrow[10+c] = (f16)fx1[c];
      for (int c = 0; c < 23; c++) lrow[33+c] = (f16)fx2[c];
      for (int c = 56; c < 64; c++) lrow[c] = (f16)0.f;
    } else {
      for (int c = 0; c < 64; c++) lrow[c] = (f16)0.f;
    }
  }
  __syncthreads();
  int wv = tid>>6, lane = tid&63, lg = lane>>4, lr = lane&15;
  f16x8 Bf[4][2];
  #pragma unroll
  for (int nt = 0; nt < 4; nt++) {
    #pragma unroll
    for (int ks = 0; ks < 2; ks++) {
      int n = nt*16 + lr;
      int kb = ks*32 + lg*8;
      f16x8 w;
      if (kb < 56) {
        float4 w0 = *(const float4*)(Wgeo + n*56 + kb);
        float4 w1 = *(const float4*)(Wgeo + n*56 + kb + 4);
        w[0]=(f16)w0.x; w[1]=(f16)w0.y; w[2]=(f16)w0.z; w[3]=(f16)w0.w;
        w[4]=(f16)w1.x; w[5]=(f16)w1.y; w[6]=(f16)w1.z; w[7]=(f16)w1.w;
      } else {
        #pragma unroll
        for (int j2 = 0; j2 < 8; j2++) w[j2] = (f16)0.f;
      }
      Bf[nt][ks] = w;
    }
  }
  float ssum[4] = {0,0,0,0}, ssq[4] = {0,0,0,0};
  for (int mt = 0; mt < 4; mt++) {
    int rbase = wv*64 + mt*16;
    f16x8 A0 = *(const f16x8*)(lds + (rbase+lr)*72 + lg*8);
    f16x8 A1 = *(const f16x8*)(lds + (rbase+lr)*72 + 32 + lg*8);
    f32x4 acc[4];
    #pragma unroll
    for (int nt = 0; nt < 4; nt++) { acc[nt][0]=0.f; acc[nt][1]=0.f; acc[nt][2]=0.f; acc[nt][3]=0.f; }
    #pragma unroll
    for (int nt = 0; nt < 4; nt++) {
      acc[nt] = __builtin_amdgcn_mfma_f32_16x16x32_f16(A0, Bf[nt][0], acc[nt], 0, 0, 0);
      acc[nt] = __builtin_amdgcn_mfma_f32_16x16x32_f16(A1, Bf[nt][1], acc[nt], 0, 0, 0);
    }
    #pragma unroll
    for (int nt = 0; nt < 4; nt++) {
      int n = nt*16 + lr;
      float bg = bgeo[n];
      #pragma unroll
      for (int rg = 0; rg < 4; rg++) {
        int rloc = rbase + lg*4 + rg;
        int p = base + rloc;
        bool valid = (p < c0) || (p >= c0p && p < c0p + c1);
        float z = valid ? (acc[nt][rg] + bg) : 0.f;
        ssum[nt] += z; ssq[nt] += z*z;
        lds[rloc*72 + n] = (f16)z;
      }
    }
  }
  #pragma unroll
  for (int nt = 0; nt < 4; nt++) {
    float v = ssum[nt]; v += __shfl_xor(v, 16); v += __shfl_xor(v, 32);
    float w = ssq[nt];  w += __shfl_xor(w, 16); w += __shfl_xor(w, 32);
    if (lane < 16) { atomicAdd(&sstat[nt*16+lane][0], v); atomicAdd(&sstat[nt*16+lane][1], w); }
  }
  __syncthreads();
  {
    int p = base + tid;
    #pragma unroll
    for (int c = 0; c < 8; c++) {
      f16x8 v = *(const f16x8*)(lds + tid*72 + c*8);
      *(f16x8*)(zgeo + (size_t)p*64 + c*8) = v;
    }
  }
  if (tid < 128) {
    float v = ((float*)sstat)[tid];
    if (v != 0.f) atomicAdd(&gstats[tid], v);
  }
}

// ---------------- grid barrier (all blocks co-resident) ----------------
__device__ __forceinline__ void gridbar(int* bar)
{
  __syncthreads();
  if (threadIdx.x == 0) {
    __threadfence();
    int g = __hip_atomic_load(&bar[1], __ATOMIC_RELAXED, __HIP_MEMORY_SCOPE_AGENT);
    int a = __hip_atomic_fetch_add(&bar[0], 1, __ATOMIC_ACQ_REL, __HIP_MEMORY_SCOPE_AGENT);
    if (a == GRID_MEGA-1) {
      __hip_atomic_store(&bar[0], 0, __ATOMIC_RELAXED, __HIP_MEMORY_SCOPE_AGENT);
      __hip_atomic_fetch_add(&bar[1], 1, __ATOMIC_RELEASE, __HIP_MEMORY_SCOPE_AGENT);
    } else {
      int iter = 0;
      while (__hip_atomic_load(&bar[1], __ATOMIC_ACQUIRE, __HIP_MEMORY_SCOPE_AGENT) == g) {
        __builtin_amdgcn_s_sleep(32);
        if (++iter > (1<<20)) break;   // failsafe: no hang
      }
    }
    __threadfence();   // acquire side: invalidate stale L1/L2 lines
  }
  __syncthreads();
}

// ---------------- mega kernel: 3 interactions x (layer0 + 3 hidden + scatter) ----------------
__global__ __launch_bounds__(256, 4) void k_mega(
    const f16* __restrict__ nf0, f16* __restrict__ nf1, f16* __restrict__ nf2,
    const f16* __restrict__ zgeo,
    const f16* __restrict__ W0h, const f16* __restrict__ Wrh,
    const float* __restrict__ b0all, const float* __restrict__ brall,
    const float* __restrict__ bngall, const float* __restrict__ bnball,
    const float* __restrict__ att,
    const float* __restrict__ g_geo, const float* __restrict__ be_geo,
    float* __restrict__ stats, const int* __restrict__ sc,
    const int* __restrict__ ip, const int* __restrict__ jp, const int* __restrict__ kp,
    const int* __restrict__ invp, const unsigned char* __restrict__ dbr,
    const int* __restrict__ startn,
    f16* __restrict__ z3a, f16* __restrict__ z3b, f16* __restrict__ z3c,
    float* __restrict__ outbase, int* __restrict__ bar)
{
  __shared__ f16 ldsa[64*200];            // staging (layer0) / per-wave transpose region
  __shared__ float geoscale[64], geoshift[64];
  __shared__ float lscale[2][64], lshift[2][64];
  __shared__ float sstat[256];
  int tid = threadIdx.x;
  int wv = tid>>6, lane = tid&63, lg = lane>>4, lr = lane&15;
  int c0 = sc[4], c0p = sc[5], c1 = sc[6];
  float att0 = att[0], att1 = att[1];
  if (tid < 64) {
    float s = stats[tid*2], sq = stats[tid*2+1];
    float mean = s * (1.f/(float)E_TRIP);
    float var  = sq * (1.f/(float)E_TRIP) - mean*mean;
    float rstd = rsqrtf(var + EPSF);
    float scl = g_geo[tid]*rstd;
    geoscale[tid] = scl;
    geoshift[tid] = be_geo[tid] - mean*scl;
  }
  __syncthreads();

  f16x8 za[SLOTS], zb[SLOTS];

  for (int t = 0; t < 3; t++) {
    const f16* nfcur = (t==0) ? nf0 : (t==1 ? nf1 : nf2);
    f16* nfnext = (t==0) ? nf1 : nf2;
    f16* zc = (t==0) ? z3a : (t==1 ? z3b : z3c);
    const f16* W0 = W0h + t*32768;
    const f16* Wr = Wrh + t*24576;
    const float* b0p = b0all + t*128;
    const float* brp = brall + t*384;
    const float* bng = bngall + t*512;
    const float* bnb = bnball + t*512;

    // =================== layer 0 (K=256) ===================
    float s0s[4]={0,0,0,0}, s0q[4]={0,0,0,0}, s1s[4]={0,0,0,0}, s1q[4]={0,0,0,0};
    sstat[tid] = 0.f;
    #pragma unroll
    for (int s = 0; s < SLOTS; s++) {
      int tile = blockIdx.x + s*GRID_MEGA;
      int rowbase = tile*64;
      bool tv = tile < NTILE64;
      __syncthreads();
      if (tv && wv < 3) {
        int r = lane, p = rowbase + r;
        bool valid = (p < c0) || (p >= c0p && p < c0p + c1);
        const int* ida = (wv==0) ? ip : (wv==1 ? jp : kp);
        f16* dst = ldsa + r*200 + wv*64;
        if (valid) {
          const f16* src = nfcur + (size_t)ida[p]*64;
          #pragma unroll
          for (int c = 0; c < 8; c++) *(f16x8*)(dst + c*8) = *(const f16x8*)(src + c*8);
        } else {
          f16x8 u;
          #pragma unroll
          for (int j2 = 0; j2 < 8; j2++) u[j2] = (f16)0.f;
          #pragma unroll
          for (int c = 0; c < 8; c++) *(f16x8*)(dst + c*8) = u;
        }
      }
      __syncthreads();
      if (tv) {
        int branch = (rowbase >= c0p) ? 1 : 0;
        int pr = rowbase + wv*16 + lr;
        bool vr = (pr < c0) || (pr >= c0p && pr < c0p + c1);
        const f16* Wb = W0 + branch*16384;
        f32x4 acc[4];
        #pragma unroll
        for (int nt = 0; nt < 4; nt++) { acc[nt][0]=0.f; acc[nt][1]=0.f; acc[nt][2]=0.f; acc[nt][3]=0.f; }
        #pragma unroll
        for (int ks = 0; ks < 6; ks++) {
          f16x8 A = *(const f16x8*)(ldsa + (wv*16+lr)*200 + ks*32 + lg*8);
          #pragma unroll
          for (int nt = 0; nt < 4; nt++) {
            f16x8 B = *(const f16x8*)(Wb + (nt*16+lr)*256 + ks*32 + lg*8);
            acc[nt] = __builtin_amdgcn_mfma_f32_16x16x32_f16(A, B, acc[nt], 0, 0, 0);
          }
        }
        #pragma unroll
        for (int k2 = 0; k2 < 2; k2++) {
          f16x8 raw = *(const f16x8*)(zgeo + (size_t)pr*64 + k2*32 + lg*8);
          f16x8 A;
          #pragma unroll
          for (int j2 = 0; j2 < 8; j2++) {
            int f = k2*32 + lg*8 + j2;
            float x = vr ? fmaxf((float)raw[j2]*geoscale[f] + geoshift[f], 0.f) : 0.f;
            A[j2] = (f16)x;
          }
          #pragma unroll
          for (int nt = 0; nt < 4; nt++) {
            f16x8 B = *(const f16x8*)(Wb + (nt*16+lr)*256 + 192 + k2*32 + lg*8);
            acc[nt] = __builtin_amdgcn_mfma_f32_16x16x32_f16(A, B, acc[nt], 0, 0, 0);
          }
        }
        f16* my = ldsa + wv*16*200;
        #pragma unroll
        for (int nt = 0; nt < 4; nt++) {
          int n = nt*16 + lr;
          float bias = b0p[branch*64 + n];
          #pragma unroll
          for (int rg = 0; rg < 4; rg++) {
            int rloc = lg*4 + rg;
            int p = rowbase + wv*16 + rloc;
            bool valid = (p < c0) || (p >= c0p && p < c0p + c1);
            float z = valid ? (acc[nt][rg] + bias) : 0.f;
            if (branch) { s1s[nt] += z; s1q[nt] += z*z; } else { s0s[nt] += z; s0q[nt] += z*z; }
            my[rloc*72 + n] = (f16)z;
          }
        }
        za[s] = *(const f16x8*)(my + lr*72 + lg*8);
        zb[s] = *(const f16x8*)(my + lr*72 + 32 + lg*8);
      } else {
        #pragma unroll
        for (int j2 = 0; j2 < 8; j2++) { za[s][j2] = (f16)0.f; zb[s][j2] = (f16)0.f; }
      }
    }
    // stats flush
    #pragma unroll
    for (int nt = 0; nt < 4; nt++) {
      float v, w;
      v = s0s[nt]; v += __shfl_xor(v,16); v += __shfl_xor(v,32);
      w = s0q[nt]; w += __shfl_xor(w,16); w += __shfl_xor(w,32);
      if (lane < 16) { atomicAdd(&sstat[(nt*16+lane)*2], v); atomicAdd(&sstat[(nt*16+lane)*2+1], w); }
      v = s1s[nt]; v += __shfl_xor(v,16); v += __shfl_xor(v,32);
      w = s1q[nt]; w += __shfl_xor(w,16); w += __shfl_xor(w,32);
      if (lane < 16) { atomicAdd(&sstat[128+(nt*16+lane)*2], v); atomicAdd(&sstat[128+(nt*16+lane)*2+1], w); }
    }
    __syncthreads();
    {
      float* stl = stats + (size_t)(1 + t*4 + 0)*256;
      float v = sstat[tid];
      if (v != 0.f) atomicAdd(&stl[tid], v);
    }
    gridbar(bar);
    {
      float* stl = stats + (size_t)(1 + t*4 + 0)*256;
      if (tid < 128) {
        int b = tid>>6, n = tid&63;
        int cb = b ? c1 : c0; if (cb < 1) cb = 1;
        float inv = 1.f/(float)cb;
        float sm = __hip_atomic_load(&stl[(b*64+n)*2], __ATOMIC_ACQUIRE, __HIP_MEMORY_SCOPE_AGENT);
        float sq = __hip_atomic_load(&stl[(b*64+n)*2+1], __ATOMIC_ACQUIRE, __HIP_MEMORY_SCOPE_AGENT);
        float mean = sm*inv, var = sq*inv - mean*mean;
        float rstd = rsqrtf(var + EPSF);
        float scl = bng[b*256 + 0*64 + n]*rstd;
        lscale[b][n] = scl;
        lshift[b][n] = bnb[b*256 + 0*64 + n] - mean*scl;
      }
    }
    __syncthreads();

    // =================== hidden layers h=0..2 (K=64) ===================
    for (int h = 0; h < 3; h++) {
      #pragma unroll
      for (int nt = 0; nt < 4; nt++) { s0s[nt]=0.f; s0q[nt]=0.f; s1s[nt]=0.f; s1q[nt]=0.f; }
      sstat[tid] = 0.f;
      __syncthreads();
      #pragma unroll
      for (int s = 0; s < SLOTS; s++) {
        int tile = blockIdx.x + s*GRID_MEGA;
        if (tile >= NTILE64) continue;
        int rowbase = tile*64;
        int branch = (rowbase >= c0p) ? 1 : 0;
        f16x8 A0, A1;
        #pragma unroll
        for (int j2 = 0; j2 < 8; j2++) {
          int f0 = lg*8 + j2;
          float x0 = fmaxf((float)za[s][j2]*lscale[branch][f0] + lshift[branch][f0], 0.f);
          A0[j2] = (f16)x0;
          int f1 = 32 + lg*8 + j2;
          float x1 = fmaxf((float)zb[s][j2]*lscale[branch][f1] + lshift[branch][f1], 0.f);
          A1[j2] = (f16)x1;
        }
        const f16* Wb = Wr + branch*12288 + h*4096;
        f32x4 acc[4];
        #pragma unroll
        for (int nt = 0; nt < 4; nt++) { acc[nt][0]=0.f; acc[nt][1]=0.f; acc[nt][2]=0.f; acc[nt][3]=0.f; }
        #pragma unroll
        for (int nt = 0; nt < 4; nt++) {
          f16x8 B0 = *(const f16x8*)(Wb + (nt*16+lr)*64 + lg*8);
          acc[nt] = __builtin_amdgcn_mfma_f32_16x16x32_f16(A0, B0, acc[nt], 0, 0, 0);
          f16x8 B1 = *(const f16x8*)(Wb + (nt*16+lr)*64 + 32 + lg*8);
          acc[nt] = __builtin_amdgcn_mfma_f32_16x16x32_f16(A1, B1, acc[nt], 0, 0, 0);
        }
        f16* my = ldsa + wv*16*200;
        #pragma unroll
        for (int nt = 0; nt < 4; nt++) {
          int n = nt*16 + lr;
          float bias = brp[branch*192 + h*64 + n];
          #pragma unroll
          for (int rg = 0; rg < 4; rg++) {
            int rloc = lg*4 + rg;
            int p = rowbase + wv*16 + rloc;
            bool valid = (p < c0) || (p >= c0p && p < c0p + c1);
            float z = valid ? (acc[nt][rg] + bias) : 0.f;
            if (branch) { s1s[nt] += z; s1q[nt] += z*z; } else { s0s[nt] += z; s0q[nt] += z*z; }
            my[rloc*72 + n] = (f16)z;
          }
        }
        za[s] = *(const f16x8*)(my + lr*72 + lg*8);
        zb[s] = *(const f16x8*)(my + lr*72 + 32 + lg*8);
        if (h == 2) {
          int pr = rowbase + wv*16 + lr;
          bool vr = (pr < c0) || (pr >= c0p && pr < c0p + c1);
          if (vr) {
            int pos = invp[pr];
            *(f16x8*)(zc + (size_t)pos*64 + lg*8) = za[s];
            *(f16x8*)(zc + (size_t)pos*64 + 32 + lg*8) = zb[s];
          }
        }
      }
      // stats flush
      #pragma unroll
      for (int nt = 0; nt < 4; nt++) {
        float v, w;
        v = s0s[nt]; v += __shfl_xor(v,16); v += __shfl_xor(v,32);
        w = s0q[nt]; w += __shfl_xor(w,16); w += __shfl_xor(w,32);
        if (lane < 16) { atomicAdd(&sstat[(nt*16+lane)*2], v); atomicAdd(&sstat[(nt*16+lane)*2+1], w); }
        v = s1s[nt]; v += __shfl_xor(v,16); v += __shfl_xor(v,32);
        w = s1q[nt]; w += __shfl_xor(w,16); w += __shfl_xor(w,32);
        if (lane < 16) { atomicAdd(&sstat[128+(nt*16+lane)*2], v); atomicAdd(&sstat[128+(nt*16+lane)*2+1], w); }
      }
      __syncthreads();
      {
        float* stl = stats + (size_t)(1 + t*4 + h + 1)*256;
        float v = sstat[tid];
        if (v != 0.f) atomicAdd(&stl[tid], v);
      }
      gridbar(bar);
      {
        float* stl = stats + (size_t)(1 + t*4 + h + 1)*256;
        int l = h + 1;
        if (tid < 128) {
          int b = tid>>6, n = tid&63;
          int cb = b ? c1 : c0; if (cb < 1) cb = 1;
          float inv = 1.f/(float)cb;
          float sm = __hip_atomic_load(&stl[(b*64+n)*2], __ATOMIC_ACQUIRE, __HIP_MEMORY_SCOPE_AGENT);
          float sq = __hip_atomic_load(&stl[(b*64+n)*2+1], __ATOMIC_ACQUIRE, __HIP_MEMORY_SCOPE_AGENT);
          float mean = sm*inv, var = sq*inv - mean*mean;
          float rstd = rsqrtf(var + EPSF);
          float scl = bng[b*256 + l*64 + n]*rstd;
          lscale[b][n] = scl;
          lshift[b][n] = bnb[b*256 + l*64 + n] - mean*scl;
        }
      }
      __syncthreads();
    }

    // =================== scatter (segment sum, sorted rows) ===================
    {
      float* outt = outbase + (size_t)t*NN*64;
      int es = lane>>3, q = lane&7;
      for (int n = blockIdx.x*4 + wv; n < NN; n += GRID_MEGA*4) {
        int s0e = startn[n], e0e = startn[n+1];
        float acc[8] = {0,0,0,0,0,0,0,0};
        for (int t0 = s0e; t0 < e0e; t0 += 8) {
          int tt = t0 + es;
          bool act = tt < e0e;
          int rr = act ? tt : s0e;
          f16x8 raw = *(const f16x8*)(zc + (size_t)rr*64 + q*8);
          if (act) {
            int b = (int)dbr[rr];
            float a = b ? att1 : att0;
            #pragma unroll
            for (int j2 = 0; j2 < 8; j2++) {
              int f = q*8 + j2;
              float x = (float)raw[j2]*lscale[b][f] + lshift[b][f];
              acc[j2] += fmaxf(x, 0.f) * a;
            }
          }
        }
        #pragma unroll
        for (int j2 = 0; j2 < 8; j2++) {
          acc[j2] += __shfl_xor(acc[j2], 8);
          acc[j2] += __shfl_xor(acc[j2], 16);
          acc[j2] += __shfl_xor(acc[j2], 32);
        }
        if (es == 0) {
          float4 lo, hi;
          lo.x=acc[0]; lo.y=acc[1]; lo.z=acc[2]; lo.w=acc[3];
          hi.x=acc[4]; hi.y=acc[5]; hi.z=acc[6]; hi.w=acc[7];
          *(float4*)(outt + (size_t)n*64 + q*8) = lo;
          *(float4*)(outt + (size_t)n*64 + q*8 + 4) = hi;
          if (t < 2) {
            f16x8 hh;
            #pragma unroll
            for (int j2 = 0; j2 < 8; j2++) hh[j2] = (f16)acc[j2];
            *(f16x8*)(nfnext + (size_t)n*64 + q*8) = hh;
          }
        }
      }
    }
    gridbar(bar);
  }
}

extern "C" void kernel_launch(void* const* d_in, const int* in_sizes, int n_in,
                              void* d_out, int out_size, void* d_ws, size_t ws_size,
                              hipStream_t stream)
{
  const float* input_feature = (const float*)d_in[0];
  const float* coords   = (const float*)d_in[1];
  const float* face_x   = (const float*)d_in[3];
  const float* att      = (const float*)d_in[4];
  const float* W_geo    = (const float*)d_in[5];
  const float* b_geo    = (const float*)d_in[6];
  const float* g_geo    = (const float*)d_in[7];
  const float* be_geo   = (const float*)d_in[8];
  const float* spnn_W0  = (const float*)d_in[9];
  const float* spnn_b0  = (const float*)d_in[10];
  const float* spnn_Wr  = (const float*)d_in[11];
  const float* spnn_br  = (const float*)d_in[12];
  const float* bn_g     = (const float*)d_in[13];
  const float* bn_b     = (const float*)d_in[14];
  const int* ewf  = (const int*)d_in[15];
  const int* eidx = (const int*)d_in[16];
  const int* exjk = (const int*)d_in[17];
  const int* exij = (const int*)d_in[18];
  float* out = (float*)d_out;
  char* ws = (char*)d_ws;

  size_t off = 0;
  auto take = [&](size_t bytes) -> char* {
    size_t o = off; off = (off + bytes + 255) & ~(size_t)255; return ws + o;
  };
  int*   sc     = (int*)take(256);
  int*   bar    = (int*)take(256);
  float* stats  = (float*)take(13*256*sizeof(float));
  int*   cnt    = (int*)take(sizeof(int)*NN);
  int*   startn = (int*)take(sizeof(int)*(NN+1));
  int*   curn   = (int*)take(sizeof(int)*NN);
  int*   btot   = (int*)take(sizeof(int)*256);
  unsigned char* biedge = (unsigned char*)take(E_TRIP);
  unsigned char* dbr    = (unsigned char*)take(EPAD);
  int* epos = (int*)take(sizeof(int)*EPAD);
  int* ip   = (int*)take(sizeof(int)*EPAD);
  int* jp   = (int*)take(sizeof(int)*EPAD);
  int* kp   = (int*)take(sizeof(int)*EPAD);
  int* invp = (int*)take(sizeof(int)*EPAD);
  f16* W0h  = (f16*)take(sizeof(f16)*3*2*64*256);
  f16* Wrh  = (f16*)take(sizeof(f16)*3*2*3*64*64);
  f16* nf0  = (f16*)take(sizeof(f16)*(size_t)NN*64);
  f16* nf1  = (f16*)take(sizeof(f16)*(size_t)NN*64);
  f16* zgeo = (f16*)take(sizeof(f16)*(size_t)EPAD*64);
  size_t Z3SZ = sizeof(f16)*(size_t)EPAD*64;
  f16* z3a  = (f16*)take(Z3SZ);
  if (off > ws_size) return;  // mandatory set must fit
  // optional (graceful fallback relies on gridbar fences for coherence)
  f16* nf2 = (off + sizeof(f16)*(size_t)NN*64 + 256 <= ws_size) ? (f16*)take(sizeof(f16)*(size_t)NN*64) : nf0;
  f16* z3b = (off + Z3SZ + 256 <= ws_size) ? (f16*)take(Z3SZ) : z3a;
  f16* z3c = (off + Z3SZ + 256 <= ws_size) ? (f16*)take(Z3SZ) : z3a;

  hipMemsetAsync(sc, 0, 512 + 13*256*sizeof(float), stream);   // sc + bar + stats (contiguous takes)
  hipMemsetAsync(cnt, 0, sizeof(int)*NN, stream);

  k_count    <<<1954, 256, 0, stream>>>(ewf, exij, exjk, biedge, sc);
  k_scal     <<<1, 1, 0, stream>>>(sc);
  k_partition<<<1954, 256, 0, stream>>>(biedge, eidx, sc, epos, ip, jp, kp);
  k_cvt      <<<25673, 256, 0, stream>>>(spnn_W0, spnn_Wr, input_feature, W0h, Wrh, nf0);
  k_hist <<<1954, 256, 0, stream>>>(ip, sc, cnt);
  k_scan1<<<196, 512, 0, stream>>>(cnt, startn, btot);
  k_scan2<<<1, 256, 0, stream>>>(btot);
  k_scan3<<<196, 512, 0, stream>>>(startn, curn, btot, sc);
  k_place<<<1954, 256, 0, stream>>>(ip, sc, curn, invp, dbr);
  k_geo  <<<EPAD/256, 256, 0, stream>>>(coords, face_x, ewf, exij, exjk, W_geo, b_geo,
                                        sc, epos, ip, jp, kp, zgeo, stats);
  k_mega <<<GRID_MEGA, 256, 0, stream>>>(nf0, nf1, nf2, zgeo, W0h, Wrh,
                                         spnn_b0, spnn_br, bn_g, bn_b, att,
                                         g_geo, be_geo, stats, sc, ip, jp, kp,
                                         invp, dbr, startn, z3a, z3b, z3c, out, bar);
}

// Round 8
// 1647.083 us; speedup vs baseline: 3.2049x; 3.2049x over previous
//
#include <hip/hip_runtime.h>

#define E_TRIP 500000
#define EPAD   500224              // multiple of 256; >= c0_pad + c1 always
#define NTILE64 (EPAD/64)          // 7816
#define NBLK256 (EPAD/256)         // 1954
#define NN 100000
#define EPSF 1e-5f
#define RSTAT 64                   // stats replication factor (kills atomic tail contention)

typedef _Float16 f16;
typedef _Float16 f16x8 __attribute__((ext_vector_type(8)));
typedef float f32x4 __attribute__((ext_vector_type(4)));

// ---------------- prep ----------------
__global__ __launch_bounds__(256) void k_count(const int* __restrict__ ewf,
    const int* __restrict__ exij, const int* __restrict__ exjk,
    unsigned char* __restrict__ biedge, int* __restrict__ sc)
{
  int e = blockIdx.x*256 + threadIdx.x;
  bool active = e < E_TRIP;
  int b = 0;
  if (active) {
    int fij = ewf[exij[e]];
    int fjk = ewf[exjk[e]];
    b = (fij == fjk) ? 0 : 1;
    biedge[e] = (unsigned char)b;
  }
  unsigned long long m0 = __ballot(active && b==0);
  unsigned long long m1 = __ballot(active && b==1);
  int lane = threadIdx.x & 63;
  if (m0 && lane == (__ffsll((long long)m0)-1)) atomicAdd(&sc[0], (int)__popcll(m0));
  if (m1 && lane == (__ffsll((long long)m1)-1)) atomicAdd(&sc[1], (int)__popcll(m1));
}

__global__ void k_scal(int* sc)
{
  int c0 = sc[0], c1 = sc[1];
  int c0p = (c0 + 63) & ~63;
  sc[2] = 0;      // cursor branch0
  sc[3] = c0p;    // cursor branch1
  sc[4] = c0;
  sc[5] = c0p;
  sc[6] = c1;
}

__global__ __launch_bounds__(256) void k_partition(const unsigned char* __restrict__ biedge,
    const int* __restrict__ eidx, int* __restrict__ sc,
    int* __restrict__ epos, int* __restrict__ ip, int* __restrict__ jp, int* __restrict__ kp)
{
  int e = blockIdx.x*256 + threadIdx.x;
  bool active = e < E_TRIP;
  int b = active ? (int)biedge[e] : 0;
  unsigned long long m0 = __ballot(active && b==0);
  unsigned long long m1 = __ballot(active && b==1);
  if (active) {
    unsigned long long m = b ? m1 : m0;
    unsigned pre = __builtin_amdgcn_mbcnt_lo((unsigned)m, 0u);
    pre = __builtin_amdgcn_mbcnt_hi((unsigned)(m >> 32), pre);
    int leader = (int)__ffsll((long long)m) - 1;
    int lane = threadIdx.x & 63;
    int base = 0;
    if (lane == leader) base = atomicAdd(&sc[2+b], (int)__popcll(m));
    base = __shfl(base, leader);
    int pos = base + (int)pre;
    epos[pos] = e;
    ip[pos] = eidx[e];
    jp[pos] = eidx[E_TRIP + e];
    kp[pos] = eidx[2*E_TRIP + e];
  }
}

__global__ __launch_bounds__(256) void k_cvt(const float* __restrict__ W0,
    const float* __restrict__ Wr, const float* __restrict__ nf,
    f16* __restrict__ W0h, f16* __restrict__ Wrh, f16* __restrict__ nfh)
{
  int i = blockIdx.x*256 + threadIdx.x;
  if (i < 98304) W0h[i] = (f16)W0[i];
  else if (i < 98304 + 73728) Wrh[i - 98304] = (f16)Wr[i - 98304];
  else { int j = i - 172032; if (j < NN*64) nfh[j] = (f16)nf[j]; }
}

// ---- destination counting sort (runs once; i is interaction-invariant) ----
__global__ __launch_bounds__(256) void k_hist(const int* __restrict__ ip,
    const int* __restrict__ sc, int* __restrict__ cnt)
{
  int p = blockIdx.x*256 + threadIdx.x;
  int c0 = sc[4], c0p = sc[5], c1 = sc[6];
  bool valid = (p < c0) || (p >= c0p && p < c0p + c1);
  if (valid) atomicAdd(&cnt[ip[p]], 1);
}

__global__ __launch_bounds__(512) void k_scan1(const int* __restrict__ cnt,
    int* __restrict__ start, int* __restrict__ btot)
{
  __shared__ int s[512];
  int tid = threadIdx.x;
  int g = blockIdx.x*512 + tid;
  int x = (g < NN) ? cnt[g] : 0;
  s[tid] = x; __syncthreads();
  #pragma unroll
  for (int off = 1; off < 512; off <<= 1) {
    int v = (tid >= off) ? s[tid-off] : 0;
    __syncthreads();
    s[tid] += v;
    __syncthreads();
  }
  if (g < NN) start[g] = s[tid] - x;   // exclusive within chunk
  if (tid == 511) btot[blockIdx.x] = s[511];
}

__global__ __launch_bounds__(256) void k_scan2(int* __restrict__ btot)
{
  __shared__ int s[256];
  int tid = threadIdx.x;
  int x = (tid < 196) ? btot[tid] : 0;
  s[tid] = x; __syncthreads();
  #pragma unroll
  for (int off = 1; off < 256; off <<= 1) {
    int v = (tid >= off) ? s[tid-off] : 0;
    __syncthreads();
    s[tid] += v;
    __syncthreads();
  }
  if (tid < 196) btot[tid] = s[tid] - x;  // exclusive
}

__global__ __launch_bounds__(512) void k_scan3(int* __restrict__ start,
    int* __restrict__ cur, const int* __restrict__ btot, const int* __restrict__ sc)
{
  int tid = threadIdx.x;
  int g = blockIdx.x*512 + tid;
  if (g < NN) {
    int v = start[g] + btot[blockIdx.x];
    start[g] = v;
    cur[g] = v;
  }
  if (g == 0) start[NN] = sc[4] + sc[6];
}

__global__ __launch_bounds__(256) void k_place(const int* __restrict__ ip,
    const int* __restrict__ sc, int* __restrict__ cur, int* __restrict__ dperm)
{
  int p = blockIdx.x*256 + threadIdx.x;
  int c0 = sc[4], c0p = sc[5], c1 = sc[6];
  bool valid = (p < c0) || (p >= c0p && p < c0p + c1);
  if (valid) {
    int pos = atomicAdd(&cur[ip[p]], 1);
    dperm[pos] = p;
  }
}

// ---------------- geo MLP input layer ----------------
__global__ __launch_bounds__(256) void k_geo(
    const float* __restrict__ coords, const float* __restrict__ facex,
    const int* __restrict__ ewf, const int* __restrict__ exij, const int* __restrict__ exjk,
    const float* __restrict__ Wgeo, const float* __restrict__ bgeo,
    const int* __restrict__ sc, const int* __restrict__ epos,
    const int* __restrict__ ip, const int* __restrict__ jp, const int* __restrict__ kp,
    f16* __restrict__ zgeo, float* __restrict__ gstats)
{
  __shared__ f16 lds[256*72];         // 256 rows x 64 feats (+8 pad) f16
  __shared__ float sstat[64][2];
  int tid = threadIdx.x;
  int base = blockIdx.x*256;
  int c0 = sc[4], c0p = sc[5], c1 = sc[6];
  if (tid < 128) ((float*)sstat)[tid] = 0.f;
  // phase A: one thread builds one row's 56 features (f16)
  {
    int p = base + tid;
    bool valid = (p < c0) || (p >= c0p && p < c0p + c1);
    f16* lrow = lds + tid*72;
    if (valid) {
      int e = epos[p];
      int ii = ip[p], jj = jp[p], kk = kp[p];
      float cix = coords[ii*3+0], ciy = coords[ii*3+1], ciz = coords[ii*3+2];
      float cjx = coords[jj*3+0], cjy = coords[jj*3+1], cjz = coords[jj*3+2];
      float ckx = coords[kk*3+0], cky = coords[kk*3+1], ckz = coords[kk*3+2];
      float v1x = cjx-cix, v1y = cjy-ciy, v1z = cjz-ciz;
      float v2x = ckx-cjx, v2y = cky-cjy, v2z = ckz-cjz;
      float dij = sqrtf(v1x*v1x + v1y*v1y + v1z*v1z);
      float djk = sqrtf(v2x*v2x + v2y*v2y + v2z*v2z);
      float cx = v1y*v2z - v1z*v2y;
      float cy = v1z*v2x - v1x*v2z;
      float cz = v1x*v2y - v1y*v2x;
      float theta = atan2f(sqrtf(cx*cx+cy*cy+cz*cz), v1x*v2x+v1y*v2y+v1z*v2z);
      lrow[0]=(f16)dij; lrow[1]=(f16)djk; lrow[2]=(f16)theta; lrow[3]=(f16)0.f;
      lrow[4]=(f16)cjx; lrow[5]=(f16)cjy; lrow[6]=(f16)cjz;
      lrow[7]=(f16)cix; lrow[8]=(f16)ciy; lrow[9]=(f16)ciz;
      int fij = ewf[exij[e]], fjk = ewf[exjk[e]];
      const float* fx1 = facex + (size_t)fij*23;
      const float* fx2 = facex + (size_t)fjk*23;
      for (int c = 0; c < 23; c++) lrow[10+c] = (f16)fx1[c];
      for (int c = 0; c < 23; c++) lrow[33+c] = (f16)fx2[c];
      for (int c = 56; c < 64; c++) lrow[c] = (f16)0.f;
    } else {
      for (int c = 0; c < 64; c++) lrow[c] = (f16)0.f;
    }
  }
  __syncthreads();
  int wv = tid>>6, lane = tid&63, lg = lane>>4, lr = lane&15;
  // B fragments from W_geo [64 out][56 in], k padded to 64 with zeros
  f16x8 Bf[4][2];
  #pragma unroll
  for (int nt = 0; nt < 4; nt++) {
    #pragma unroll
    for (int ks = 0; ks < 2; ks++) {
      int n = nt*16 + lr;
      int kb = ks*32 + lg*8;
      f16x8 w;
      if (kb < 56) {
        float4 w0 = *(const float4*)(Wgeo + n*56 + kb);
        float4 w1 = *(const float4*)(Wgeo + n*56 + kb + 4);
        w[0]=(f16)w0.x; w[1]=(f16)w0.y; w[2]=(f16)w0.z; w[3]=(f16)w0.w;
        w[4]=(f16)w1.x; w[5]=(f16)w1.y; w[6]=(f16)w1.z; w[7]=(f16)w1.w;
      } else {
        #pragma unroll
        for (int j2 = 0; j2 < 8; j2++) w[j2] = (f16)0.f;
      }
      Bf[nt][ks] = w;
    }
  }
  float ssum[4] = {0,0,0,0}, ssq[4] = {0,0,0,0};
  for (int mt = 0; mt < 4; mt++) {
    int rbase = wv*64 + mt*16;
    f16x8 A0 = *(const f16x8*)(lds + (rbase+lr)*72 + lg*8);
    f16x8 A1 = *(const f16x8*)(lds + (rbase+lr)*72 + 32 + lg*8);
    f32x4 acc[4];
    #pragma unroll
    for (int nt = 0; nt < 4; nt++) { acc[nt][0]=0.f; acc[nt][1]=0.f; acc[nt][2]=0.f; acc[nt][3]=0.f; }
    #pragma unroll
    for (int nt = 0; nt < 4; nt++) {
      acc[nt] = __builtin_amdgcn_mfma_f32_16x16x32_f16(A0, Bf[nt][0], acc[nt], 0, 0, 0);
      acc[nt] = __builtin_amdgcn_mfma_f32_16x16x32_f16(A1, Bf[nt][1], acc[nt], 0, 0, 0);
    }
    #pragma unroll
    for (int nt = 0; nt < 4; nt++) {
      int n = nt*16 + lr;
      float bg = bgeo[n];
      #pragma unroll
      for (int rg = 0; rg < 4; rg++) {
        int rloc = rbase + lg*4 + rg;
        int p = base + rloc;
        bool valid = (p < c0) || (p >= c0p && p < c0p + c1);
        float z = valid ? (acc[nt][rg] + bg) : 0.f;
        ssum[nt] += z; ssq[nt] += z*z;
        lds[rloc*72 + n] = (f16)z;
      }
    }
  }
  #pragma unroll
  for (int nt = 0; nt < 4; nt++) {
    float v = ssum[nt]; v += __shfl_xor(v, 16); v += __shfl_xor(v, 32);
    float w = ssq[nt];  w += __shfl_xor(w, 16); w += __shfl_xor(w, 32);
    if (lane < 16) { atomicAdd(&sstat[nt*16+lane][0], v); atomicAdd(&sstat[nt*16+lane][1], w); }
  }
  __syncthreads();
  {
    int p = base + tid;
    #pragma unroll
    for (int c = 0; c < 8; c++) {
      f16x8 v = *(const f16x8*)(lds + tid*72 + c*8);
      *(f16x8*)(zgeo + (size_t)p*64 + c*8) = v;
    }
  }
  if (tid < 128) {
    float v = ((float*)sstat)[tid];
    if (v != 0.f) atomicAdd(&gstats[(blockIdx.x & (RSTAT-1))*256 + tid], v);
  }
}

// ---------------- interaction layer 0 (K=256), staged gather ----------------
__global__ __launch_bounds__(256) void k_layer0(
    const f16* __restrict__ nfsrc, const f16* __restrict__ zgeo,
    const f16* __restrict__ W0p, const float* __restrict__ b0p,
    const float* __restrict__ g_geo, const float* __restrict__ be_geo,
    const float* __restrict__ geostats, float* __restrict__ outstats,
    const int* __restrict__ sc, const int* __restrict__ ip,
    const int* __restrict__ jp, const int* __restrict__ kp,
    f16* __restrict__ z0)
{
  __shared__ f16 lds[64*264];   // 64 rows x 256 k (+8 pad)
  __shared__ float geoscale[64], geoshift[64];
  __shared__ float sstat[2][64][2];
  int tid = threadIdx.x;
  int c0 = sc[4], c0p = sc[5], c1 = sc[6];
  if (tid < 64) {
    float s = 0.f, sq = 0.f;
    #pragma unroll 8
    for (int r = 0; r < RSTAT; r++) {
      s  += geostats[r*256 + tid*2];
      sq += geostats[r*256 + tid*2 + 1];
    }
    float mean = s * (1.f/(float)E_TRIP);
    float var  = sq * (1.f/(float)E_TRIP) - mean*mean;
    float rstd = rsqrtf(var + EPSF);
    float scl = g_geo[tid]*rstd;
    geoscale[tid] = scl;
    geoshift[tid] = be_geo[tid] - mean*scl;
  }
  ((float*)sstat)[tid] = 0.f;
  __syncthreads();
  int wv = tid>>6, lane = tid&63, lg = lane>>4, lr = lane&15;
  float s0sum[4]={0,0,0,0}, s0sq[4]={0,0,0,0}, s1sum[4]={0,0,0,0}, s1sq[4]={0,0,0,0};
  for (int tile = blockIdx.x; tile < NTILE64; tile += gridDim.x) {
    int rowbase = tile*64;
    int branch = (rowbase >= c0p) ? 1 : 0;
    // phase A: stage xcat tile [64 rows][256 k] in f16
    {
      int r = tid >> 2, q = tid & 3;
      int p = rowbase + r;
      bool valid = (p < c0) || (p >= c0p && p < c0p + c1);
      f16* rowp = lds + r*264 + q*64;
      if (q < 3) {
        if (valid) {
          int idx = (q==0 ? ip : (q==1 ? jp : kp))[p];
          const f16* src = nfsrc + (size_t)idx*64;
          #pragma unroll
          for (int c = 0; c < 8; c++) *(f16x8*)(rowp + c*8) = *(const f16x8*)(src + c*8);
        } else {
          f16x8 u;
          #pragma unroll
          for (int j2 = 0; j2 < 8; j2++) u[j2] = (f16)0.f;
          #pragma unroll
          for (int c = 0; c < 8; c++) *(f16x8*)(rowp + c*8) = u;
        }
      } else {
        if (valid) {
          const f16* zg = zgeo + (size_t)p*64;
          #pragma unroll
          for (int c = 0; c < 8; c++) {
            f16x8 raw = *(const f16x8*)(zg + c*8);
            f16x8 u;
            #pragma unroll
            for (int j2 = 0; j2 < 8; j2++) {
              int f = c*8 + j2;
              float x = fmaxf((float)raw[j2]*geoscale[f] + geoshift[f], 0.f);
              u[j2] = (f16)x;
            }
            *(f16x8*)(rowp + c*8) = u;
          }
        } else {
          f16x8 u;
          #pragma unroll
          for (int j2 = 0; j2 < 8; j2++) u[j2] = (f16)0.f;
          #pragma unroll
          for (int c = 0; c < 8; c++) *(f16x8*)(rowp + c*8) = u;
        }
      }
    }
    __syncthreads();
    // phase B: each wave does 16 rows x 64 cols, K=256
    {
      int r0 = wv*16;
      const f16* Wb = W0p + branch*16384;
      f32x4 acc[4];
      #pragma unroll
      for (int nt = 0; nt < 4; nt++) { acc[nt][0]=0.f; acc[nt][1]=0.f; acc[nt][2]=0.f; acc[nt][3]=0.f; }
      #pragma unroll
      for (int ks = 0; ks < 8; ks++) {
        f16x8 A = *(const f16x8*)(lds + (r0+lr)*264 + (ks*4+lg)*8);
        #pragma unroll
        for (int nt = 0; nt < 4; nt++) {
          f16x8 B = *(const f16x8*)(Wb + (nt*16+lr)*256 + ks*32 + lg*8);
          acc[nt] = __builtin_amdgcn_mfma_f32_16x16x32_f16(A, B, acc[nt], 0, 0, 0);
        }
      }
      #pragma unroll
      for (int nt = 0; nt < 4; nt++) {
        int n = nt*16 + lr;
        float bias = b0p[branch*64 + n];
        #pragma unroll
        for (int rg = 0; rg < 4; rg++) {
          int rloc = r0 + lg*4 + rg;
          int p = rowbase + rloc;
          bool valid = (p < c0) || (p >= c0p && p < c0p + c1);
          float z = valid ? (acc[nt][rg] + bias) : 0.f;
          if (branch == 0) { s0sum[nt] += z; s0sq[nt] += z*z; }
          else             { s1sum[nt] += z; s1sq[nt] += z*z; }
          lds[rloc*264 + n] = (f16)z;
        }
      }
    }
    __syncthreads();
    // store
    {
      int r = tid>>2, q = tid&3;
      int p = rowbase + r;
      f16x8 v0 = *(const f16x8*)(lds + r*264 + q*16);
      f16x8 v1 = *(const f16x8*)(lds + r*264 + q*16 + 8);
      *(f16x8*)(z0 + (size_t)p*64 + q*16) = v0;
      *(f16x8*)(z0 + (size_t)p*64 + q*16 + 8) = v1;
    }
    __syncthreads();
  }
  #pragma unroll
  for (int nt = 0; nt < 4; nt++) {
    float v, w;
    v = s0sum[nt]; v += __shfl_xor(v,16); v += __shfl_xor(v,32);
    w = s0sq[nt];  w += __shfl_xor(w,16); w += __shfl_xor(w,32);
    if (lane < 16) { atomicAdd(&sstat[0][nt*16+lane][0], v); atomicAdd(&sstat[0][nt*16+lane][1], w); }
    v = s1sum[nt]; v += __shfl_xor(v,16); v += __shfl_xor(v,32);
    w = s1sq[nt];  w += __shfl_xor(w,16); w += __shfl_xor(w,32);
    if (lane < 16) { atomicAdd(&sstat[1][nt*16+lane][0], v); atomicAdd(&sstat[1][nt*16+lane][1], w); }
  }
  __syncthreads();
  {
    float v = ((float*)sstat)[tid];
    if (v != 0.f) atomicAdd(&outstats[(blockIdx.x & (RSTAT-1))*256 + tid], v);
  }
}

// ---------------- hidden layers (K=64) ----------------
__global__ __launch_bounds__(256) void k_hidden(
    const f16* __restrict__ zin, f16* __restrict__ zout,
    const f16* __restrict__ Wp, const float* __restrict__ biasp,
    const float* __restrict__ bngp, const float* __restrict__ bnbp,
    const float* __restrict__ instats, float* __restrict__ outstats,
    const int* __restrict__ sc)
{
  __shared__ float lscale[2][64], lshift[2][64];
  __shared__ float sstat[2][64][2];
  __shared__ f16 ldso[4][16*72];
  int tid = threadIdx.x;
  int c0 = sc[4], c0p = sc[5], c1 = sc[6];
  if (tid < 128) {
    int b = tid>>6, n = tid&63;
    int cb = b ? c1 : c0; if (cb < 1) cb = 1;
    float inv = 1.f/(float)cb;
    int idx = (b*64+n)*2;
    float s = 0.f, sq = 0.f;
    #pragma unroll 8
    for (int r = 0; r < RSTAT; r++) {
      s  += instats[r*256 + idx];
      sq += instats[r*256 + idx + 1];
    }
    float mean = s*inv, var = sq*inv - mean*mean;
    float rstd = rsqrtf(var + EPSF);
    float scl = bngp[b*256+n]*rstd;
    lscale[b][n] = scl;
    lshift[b][n] = bnbp[b*256+n] - mean*scl;
  }
  ((float*)sstat)[tid] = 0.f;
  __syncthreads();
  int wv = tid>>6, lane = tid&63, lg = lane>>4, lr = lane&15;
  f16* myldso = ldso[wv];
  float s0sum[4]={0,0,0,0}, s0sq[4]={0,0,0,0}, s1sum[4]={0,0,0,0}, s1sq[4]={0,0,0,0};
  for (int tile = blockIdx.x; tile < NTILE64; tile += gridDim.x) {
    int rowbase = tile*64;
    int branch = (rowbase >= c0p) ? 1 : 0;
    int rgl = rowbase + wv*16 + lr;
    f16x8 Af[2];
    #pragma unroll
    for (int ks = 0; ks < 2; ks++) {
      f16x8 raw = *(const f16x8*)(zin + (size_t)rgl*64 + ks*32 + lg*8);
      f16x8 A;
      #pragma unroll
      for (int j2 = 0; j2 < 8; j2++) {
        int f = ks*32 + lg*8 + j2;
        float x = fmaxf((float)raw[j2]*lscale[branch][f] + lshift[branch][f], 0.f);
        A[j2] = (f16)x;
      }
      Af[ks] = A;
    }
    f32x4 acc[4];
    #pragma unroll
    for (int nt = 0; nt < 4; nt++) { acc[nt][0]=0.f; acc[nt][1]=0.f; acc[nt][2]=0.f; acc[nt][3]=0.f; }
    #pragma unroll
    for (int ks = 0; ks < 2; ks++) {
      #pragma unroll
      for (int nt = 0; nt < 4; nt++) {
        f16x8 B = *(const f16x8*)(Wp + branch*12288 + (nt*16+lr)*64 + ks*32 + lg*8);
        acc[nt] = __builtin_amdgcn_mfma_f32_16x16x32_f16(Af[ks], B, acc[nt], 0, 0, 0);
      }
    }
    #pragma unroll
    for (int nt = 0; nt < 4; nt++) {
      int n = nt*16 + lr;
      float bias = biasp[branch*192 + n];
      #pragma unroll
      for (int rg = 0; rg < 4; rg++) {
        int rloc = lg*4 + rg;
        int p = rowbase + wv*16 + rloc;
        bool valid = (p < c0) || (p >= c0p && p < c0p + c1);
        float z = valid ? (acc[nt][rg] + bias) : 0.f;
        if (branch == 0) { s0sum[nt] += z; s0sq[nt] += z*z; }
        else             { s1sum[nt] += z; s1sq[nt] += z*z; }
        myldso[rloc*72 + n] = (f16)z;
      }
    }
    {
      int r2 = lane>>2, q = lane&3;
      int p2 = rowbase + wv*16 + r2;
      f16x8 v0 = *(const f16x8*)(myldso + r2*72 + q*8);
      f16x8 v1 = *(const f16x8*)(myldso + r2*72 + 32 + q*8);
      *(f16x8*)(zout + (size_t)p2*64 + q*8) = v0;
      *(f16x8*)(zout + (size_t)p2*64 + 32 + q*8) = v1;
    }
  }
  #pragma unroll
  for (int nt = 0; nt < 4; nt++) {
    float v, w;
    v = s0sum[nt]; v += __shfl_xor(v,16); v += __shfl_xor(v,32);
    w = s0sq[nt];  w += __shfl_xor(w,16); w += __shfl_xor(w,32);
    if (lane < 16) { atomicAdd(&sstat[0][nt*16+lane][0], v); atomicAdd(&sstat[0][nt*16+lane][1], w); }
    v = s1sum[nt]; v += __shfl_xor(v,16); v += __shfl_xor(v,32);
    w = s1sq[nt];  w += __shfl_xor(w,16); w += __shfl_xor(w,32);
    if (lane < 16) { atomicAdd(&sstat[1][nt*16+lane][0], v); atomicAdd(&sstat[1][nt*16+lane][1], w); }
  }
  __syncthreads();
  {
    float v = ((float*)sstat)[tid];
    if (v != 0.f) atomicAdd(&outstats[(blockIdx.x & (RSTAT-1))*256 + tid], v);
  }
}

// ---------------- final BN + relu + att + destination-sorted segment sum ----------------
__global__ __launch_bounds__(256) void k_scatter(
    const f16* __restrict__ z3, const float* __restrict__ att,
    const float* __restrict__ bngp, const float* __restrict__ bnbp,
    const float* __restrict__ instats, const int* __restrict__ sc,
    const int* __restrict__ start, const int* __restrict__ dperm,
    float* __restrict__ outt, f16* __restrict__ nfh)
{
  __shared__ float lscale[2][64], lshift[2][64];
  int tid = threadIdx.x;
  int c0p = sc[5];
  {
    int c0 = sc[4], c1 = sc[6];
    if (tid < 128) {
      int b = tid>>6, n = tid&63;
      int cb = b ? c1 : c0; if (cb < 1) cb = 1;
      float inv = 1.f/(float)cb;
      int idx = (b*64+n)*2;
      float s = 0.f, sq = 0.f;
      #pragma unroll 8
      for (int r = 0; r < RSTAT; r++) {
        s  += instats[r*256 + idx];
        sq += instats[r*256 + idx + 1];
      }
      float mean = s*inv, var = sq*inv - mean*mean;
      float rstd = rsqrtf(var + EPSF);
      float scl = bngp[b*256+n]*rstd;
      lscale[b][n] = scl;
      lshift[b][n] = bnbp[b*256+n] - mean*scl;
    }
  }
  __syncthreads();
  int gid = blockIdx.x*256 + tid;
  int n = gid >> 3, q = gid & 7;
  if (n >= NN) return;
  int s = start[n];
  int e = start[n+1];
  float a0 = att[0], a1 = att[1];
  float acc[8] = {0,0,0,0,0,0,0,0};
  float sc0[8], sh0[8], sc1[8], sh1[8];
  #pragma unroll
  for (int j2 = 0; j2 < 8; j2++) {
    int f = q*8 + j2;
    sc0[j2] = lscale[0][f]; sh0[j2] = lshift[0][f];
    sc1[j2] = lscale[1][f]; sh1[j2] = lshift[1][f];
  }
  for (int t = s; t < e; t++) {
    int p = dperm[t];
    int b = (p >= c0p) ? 1 : 0;
    float a = b ? a1 : a0;
    f16x8 raw = *(const f16x8*)(z3 + (size_t)p*64 + q*8);
    #pragma unroll
    for (int j2 = 0; j2 < 8; j2++) {
      float x = (float)raw[j2]*(b ? sc1[j2] : sc0[j2]) + (b ? sh1[j2] : sh0[j2]);
      acc[j2] += fmaxf(x, 0.f) * a;   // leaky_relu identity for x>=0
    }
  }
  float4 lo, hi;
  lo.x=acc[0]; lo.y=acc[1]; lo.z=acc[2]; lo.w=acc[3];
  hi.x=acc[4]; hi.y=acc[5]; hi.z=acc[6]; hi.w=acc[7];
  *(float4*)(outt + (size_t)n*64 + q*8) = lo;
  *(float4*)(outt + (size_t)n*64 + q*8 + 4) = hi;
  f16x8 h;
  #pragma unroll
  for (int j2 = 0; j2 < 8; j2++) h[j2] = (f16)acc[j2];
  *(f16x8*)(nfh + (size_t)n*64 + q*8) = h;
}

extern "C" void kernel_launch(void* const* d_in, const int* in_sizes, int n_in,
                              void* d_out, int out_size, void* d_ws, size_t ws_size,
                              hipStream_t stream)
{
  const float* input_feature = (const float*)d_in[0];
  const float* coords   = (const float*)d_in[1];
  const float* face_x   = (const float*)d_in[3];
  const float* att      = (const float*)d_in[4];
  const float* W_geo    = (const float*)d_in[5];
  const float* b_geo    = (const float*)d_in[6];
  const float* g_geo    = (const float*)d_in[7];
  const float* be_geo   = (const float*)d_in[8];
  const float* spnn_W0  = (const float*)d_in[9];
  const float* spnn_b0  = (const float*)d_in[10];
  const float* spnn_Wr  = (const float*)d_in[11];
  const float* spnn_br  = (const float*)d_in[12];
  const float* bn_g     = (const float*)d_in[13];
  const float* bn_b     = (const float*)d_in[14];
  const int* ewf  = (const int*)d_in[15];
  const int* eidx = (const int*)d_in[16];
  const int* exjk = (const int*)d_in[17];
  const int* exij = (const int*)d_in[18];
  float* out = (float*)d_out;
  char* ws = (char*)d_ws;

  size_t off = 0;
  auto take = [&](size_t bytes) -> char* {
    size_t o = off; off = (off + bytes + 255) & ~(size_t)255; return ws + o;
  };
  const size_t STATBUF = (size_t)RSTAT*256;           // floats per stat buffer
  int*   sc     = (int*)take(256);
  float* stats  = (float*)take(13*STATBUF*sizeof(float));  // geo + 3*4 layer stat buffers, replicated
  int*   cnt    = (int*)take(sizeof(int)*NN);
  int*   startn = (int*)take(sizeof(int)*(NN+1));
  int*   curn   = (int*)take(sizeof(int)*NN);
  int*   btot   = (int*)take(sizeof(int)*256);
  int*   dperm  = (int*)take(sizeof(int)*EPAD);
  unsigned char* biedge = (unsigned char*)take(E_TRIP);
  int* epos = (int*)take(sizeof(int)*EPAD);
  int* ip   = (int*)take(sizeof(int)*EPAD);
  int* jp   = (int*)take(sizeof(int)*EPAD);
  int* kp   = (int*)take(sizeof(int)*EPAD);
  f16* W0h  = (f16*)take(sizeof(f16)*3*2*64*256);
  f16* Wrh  = (f16*)take(sizeof(f16)*3*2*3*64*64);
  f16* nf16 = (f16*)take(sizeof(f16)*(size_t)NN*64);
  f16* zgeo = (f16*)take(sizeof(f16)*(size_t)EPAD*64);
  f16* zA   = (f16*)take(sizeof(f16)*(size_t)EPAD*64);
  f16* zB   = (f16*)take(sizeof(f16)*(size_t)EPAD*64);
  if (off > ws_size) return;  // workspace insufficient; cannot run

  hipMemsetAsync(sc, 0, 256, stream);
  hipMemsetAsync(stats, 0, 13*STATBUF*sizeof(float), stream);
  hipMemsetAsync(cnt, 0, sizeof(int)*NN, stream);

  k_count    <<<1954, 256, 0, stream>>>(ewf, exij, exjk, biedge, sc);
  k_scal     <<<1, 1, 0, stream>>>(sc);
  k_partition<<<1954, 256, 0, stream>>>(biedge, eidx, sc, epos, ip, jp, kp);
  k_cvt      <<<25673, 256, 0, stream>>>(spnn_W0, spnn_Wr, input_feature, W0h, Wrh, nf16);
  // destination counting sort (i is the same for all 3 interactions)
  k_hist <<<1954, 256, 0, stream>>>(ip, sc, cnt);
  k_scan1<<<196, 512, 0, stream>>>(cnt, startn, btot);
  k_scan2<<<1, 256, 0, stream>>>(btot);
  k_scan3<<<196, 512, 0, stream>>>(startn, curn, btot, sc);
  k_place<<<1954, 256, 0, stream>>>(ip, sc, curn, dperm);

  k_geo      <<<NBLK256, 256, 0, stream>>>(coords, face_x, ewf, exij, exjk, W_geo, b_geo,
                                           sc, epos, ip, jp, kp, zgeo, stats);
  for (int t = 0; t < 3; t++) {
    float* outt = out + (size_t)t*NN*64;
    k_layer0<<<1024, 256, 0, stream>>>(nf16, zgeo,
        W0h + (size_t)t*2*64*256, spnn_b0 + t*2*64,
        g_geo, be_geo, stats, stats + (size_t)(1 + t*4)*STATBUF,
        sc, ip, jp, kp, zA);
    f16* zi = zA; f16* zo = zB;
    for (int h = 0; h < 3; h++) {
      k_hidden<<<2048, 256, 0, stream>>>(zi, zo,
          Wrh + (size_t)t*2*3*64*64 + (size_t)h*64*64,
          spnn_br + t*2*3*64 + h*64,
          bn_g + t*2*4*64 + h*64,
          bn_b + t*2*4*64 + h*64,
          stats + (size_t)(1 + t*4 + h)*STATBUF,
          stats + (size_t)(1 + t*4 + h + 1)*STATBUF,
          sc);
      f16* tmp = zi; zi = zo; zo = tmp;
    }
    k_scatter<<<(NN*8 + 255)/256, 256, 0, stream>>>(zi, att,
        bn_g + t*2*4*64 + 3*64, bn_b + t*2*4*64 + 3*64,
        stats + (size_t)(1 + t*4 + 3)*STATBUF, sc, startn, dperm, outt, nf16);
  }
}

// Round 9
// 1386.580 us; speedup vs baseline: 3.8071x; 1.1879x over previous
//
#include <hip/hip_runtime.h>

#define E_TRIP 500000
#define EPAD   500224              // multiple of 256; >= c0_pad + c1 always
#define NTILE64 (EPAD/64)          // 7816
#define NBLK256 (EPAD/256)         // 1954
#define NBLK    1954               // edge blocks (256 edges each)
#define NN 100000
#define EPSF 1e-5f
#define RSTAT 64                   // stats replication factor (kills atomic tail contention)

typedef _Float16 f16;
typedef _Float16 f16x8 __attribute__((ext_vector_type(8)));
typedef float f32x4 __attribute__((ext_vector_type(4)));

// ---------------- prep: per-block branch counts (no global atomics) ----------------
__global__ __launch_bounds__(256) void k_count(const int* __restrict__ ewf,
    const int* __restrict__ exij, const int* __restrict__ exjk,
    unsigned char* __restrict__ biedge, int* __restrict__ cb0)
{
  __shared__ int wcnt[4];
  int e = blockIdx.x*256 + threadIdx.x;
  bool active = e < E_TRIP;
  int b = 0;
  if (active) {
    int fij = ewf[exij[e]];
    int fjk = ewf[exjk[e]];
    b = (fij == fjk) ? 0 : 1;
    biedge[e] = (unsigned char)b;
  }
  unsigned long long m0 = __ballot(active && b==0);
  int lane = threadIdx.x & 63, wv = threadIdx.x >> 6;
  if (lane == 0) wcnt[wv] = (int)__popcll(m0);
  __syncthreads();
  if (threadIdx.x == 0) cb0[blockIdx.x] = wcnt[0] + wcnt[1] + wcnt[2] + wcnt[3];
}

// single block: scan per-block counts -> partition bases; sets sc[4..6]
__global__ __launch_bounds__(1024) void k_scanb(const int* __restrict__ cb0,
    int* __restrict__ base0, int* __restrict__ base1, int* __restrict__ sc)
{
  __shared__ int s[2048];
  int tid = threadIdx.x;
  int i0 = tid, i1 = tid + 1024;
  s[i0] = (i0 < NBLK) ? cb0[i0] : 0;
  s[i1] = (i1 < NBLK) ? cb0[i1] : 0;
  __syncthreads();
  for (int off = 1; off < 2048; off <<= 1) {
    int v0 = (i0 >= off) ? s[i0 - off] : 0;
    int v1 = (i1 >= off) ? s[i1 - off] : 0;
    __syncthreads();
    s[i0] += v0; s[i1] += v1;
    __syncthreads();
  }
  int c0 = s[NBLK-1];
  int c0p = (c0 + 63) & ~63;
  if (tid == 0) { sc[4] = c0; sc[5] = c0p; sc[6] = E_TRIP - c0; }
  for (int i = tid; i < NBLK; i += 1024) {
    int incl = s[i];
    int ex0 = incl - cb0[i];
    int active_before = i*256; if (active_before > E_TRIP) active_before = E_TRIP;
    base0[i] = ex0;
    base1[i] = c0p + (active_before - ex0);
  }
}

// deterministic scan-based partition (no global atomics)
__global__ __launch_bounds__(256) void k_partition(const unsigned char* __restrict__ biedge,
    const int* __restrict__ eidx, const int* __restrict__ base0, const int* __restrict__ base1,
    int* __restrict__ epos, int* __restrict__ ip, int* __restrict__ jp, int* __restrict__ kp)
{
  __shared__ int w0[4], w1[4];
  int e = blockIdx.x*256 + threadIdx.x;
  bool active = e < E_TRIP;
  int b = active ? (int)biedge[e] : 0;
  unsigned long long m0 = __ballot(active && b==0);
  unsigned long long m1 = __ballot(active && b==1);
  int lane = threadIdx.x & 63, wv = threadIdx.x >> 6;
  if (lane == 0) { w0[wv] = (int)__popcll(m0); w1[wv] = (int)__popcll(m1); }
  __syncthreads();
  int off0 = 0, off1 = 0;
  #pragma unroll
  for (int w = 0; w < 4; w++) if (w < wv) { off0 += w0[w]; off1 += w1[w]; }
  if (active) {
    unsigned long long m = b ? m1 : m0;
    unsigned pre = __builtin_amdgcn_mbcnt_lo((unsigned)m, 0u);
    pre = __builtin_amdgcn_mbcnt_hi((unsigned)(m >> 32), pre);
    int base = b ? (base1[blockIdx.x] + off1) : (base0[blockIdx.x] + off0);
    int pos = base + (int)pre;
    epos[pos] = e;
    ip[pos] = eidx[e];
    jp[pos] = eidx[E_TRIP + e];
    kp[pos] = eidx[2*E_TRIP + e];
  }
}

__global__ __launch_bounds__(256) void k_cvt(const float* __restrict__ W0,
    const float* __restrict__ Wr, const float* __restrict__ nf,
    f16* __restrict__ W0h, f16* __restrict__ Wrh, f16* __restrict__ nfh)
{
  int i = blockIdx.x*256 + threadIdx.x;
  if (i < 98304) W0h[i] = (f16)W0[i];
  else if (i < 98304 + 73728) Wrh[i - 98304] = (f16)Wr[i - 98304];
  else { int j = i - 172032; if (j < NN*64) nfh[j] = (f16)nf[j]; }
}

// ---- destination counting sort (runs once; i is interaction-invariant) ----
__global__ __launch_bounds__(256) void k_hist(const int* __restrict__ ip,
    const int* __restrict__ sc, int* __restrict__ cnt)
{
  int p = blockIdx.x*256 + threadIdx.x;
  int c0 = sc[4], c0p = sc[5], c1 = sc[6];
  bool valid = (p < c0) || (p >= c0p && p < c0p + c1);
  if (valid) atomicAdd(&cnt[ip[p]], 1);
}

__global__ __launch_bounds__(512) void k_scan1(const int* __restrict__ cnt,
    int* __restrict__ start, int* __restrict__ btot)
{
  __shared__ int s[512];
  int tid = threadIdx.x;
  int g = blockIdx.x*512 + tid;
  int x = (g < NN) ? cnt[g] : 0;
  s[tid] = x; __syncthreads();
  #pragma unroll
  for (int off = 1; off < 512; off <<= 1) {
    int v = (tid >= off) ? s[tid-off] : 0;
    __syncthreads();
    s[tid] += v;
    __syncthreads();
  }
  if (g < NN) start[g] = s[tid] - x;   // exclusive within chunk
  if (tid == 511) btot[blockIdx.x] = s[511];
}

__global__ __launch_bounds__(256) void k_scan2(int* __restrict__ btot)
{
  __shared__ int s[256];
  int tid = threadIdx.x;
  int x = (tid < 196) ? btot[tid] : 0;
  s[tid] = x; __syncthreads();
  #pragma unroll
  for (int off = 1; off < 256; off <<= 1) {
    int v = (tid >= off) ? s[tid-off] : 0;
    __syncthreads();
    s[tid] += v;
    __syncthreads();
  }
  if (tid < 196) btot[tid] = s[tid] - x;  // exclusive
}

__global__ __launch_bounds__(512) void k_scan3(int* __restrict__ start,
    int* __restrict__ cur, const int* __restrict__ btot, const int* __restrict__ sc)
{
  int tid = threadIdx.x;
  int g = blockIdx.x*512 + tid;
  if (g < NN) {
    int v = start[g] + btot[blockIdx.x];
    start[g] = v;
    cur[g] = v;
  }
  if (g == 0) start[NN] = sc[4] + sc[6];
}

__global__ __launch_bounds__(256) void k_place(const int* __restrict__ ip,
    const int* __restrict__ sc, int* __restrict__ cur, int* __restrict__ dperm)
{
  int p = blockIdx.x*256 + threadIdx.x;
  int c0 = sc[4], c0p = sc[5], c1 = sc[6];
  bool valid = (p < c0) || (p >= c0p && p < c0p + c1);
  if (valid) {
    int pos = atomicAdd(&cur[ip[p]], 1);
    dperm[pos] = p;
  }
}

// ---------------- geo MLP input layer ----------------
__global__ __launch_bounds__(256) void k_geo(
    const float* __restrict__ coords, const float* __restrict__ facex,
    const int* __restrict__ ewf, const int* __restrict__ exij, const int* __restrict__ exjk,
    const float* __restrict__ Wgeo, const float* __restrict__ bgeo,
    const int* __restrict__ sc, const int* __restrict__ epos,
    const int* __restrict__ ip, const int* __restrict__ jp, const int* __restrict__ kp,
    f16* __restrict__ zgeo, float* __restrict__ gstats)
{
  __shared__ f16 lds[256*72];         // 256 rows x 64 feats (+8 pad) f16
  __shared__ float sstat[64][2];
  int tid = threadIdx.x;
  int base = blockIdx.x*256;
  int c0 = sc[4], c0p = sc[5], c1 = sc[6];
  if (tid < 128) ((float*)sstat)[tid] = 0.f;
  // phase A: one thread builds one row's 56 features (f16)
  {
    int p = base + tid;
    bool valid = (p < c0) || (p >= c0p && p < c0p + c1);
    f16* lrow = lds + tid*72;
    if (valid) {
      int e = epos[p];
      int ii = ip[p], jj = jp[p], kk = kp[p];
      float cix = coords[ii*3+0], ciy = coords[ii*3+1], ciz = coords[ii*3+2];
      float cjx = coords[jj*3+0], cjy = coords[jj*3+1], cjz = coords[jj*3+2];
      float ckx = coords[kk*3+0], cky = coords[kk*3+1], ckz = coords[kk*3+2];
      float v1x = cjx-cix, v1y = cjy-ciy, v1z = cjz-ciz;
      float v2x = ckx-cjx, v2y = cky-cjy, v2z = ckz-cjz;
      float dij = sqrtf(v1x*v1x + v1y*v1y + v1z*v1z);
      float djk = sqrtf(v2x*v2x + v2y*v2y + v2z*v2z);
      float cx = v1y*v2z - v1z*v2y;
      float cy = v1z*v2x - v1x*v2z;
      float cz = v1x*v2y - v1y*v2x;
      float theta = atan2f(sqrtf(cx*cx+cy*cy+cz*cz), v1x*v2x+v1y*v2y+v1z*v2z);
      lrow[0]=(f16)dij; lrow[1]=(f16)djk; lrow[2]=(f16)theta; lrow[3]=(f16)0.f;
      lrow[4]=(f16)cjx; lrow[5]=(f16)cjy; lrow[6]=(f16)cjz;
      lrow[7]=(f16)cix; lrow[8]=(f16)ciy; lrow[9]=(f16)ciz;
      int fij = ewf[exij[e]], fjk = ewf[exjk[e]];
      const float* fx1 = facex + (size_t)fij*23;
      const float* fx2 = facex + (size_t)fjk*23;
      for (int c = 0; c < 23; c++) lrow[10+c] = (f16)fx1[c];
      for (int c = 0; c < 23; c++) lrow[33+c] = (f16)fx2[c];
      for (int c = 56; c < 64; c++) lrow[c] = (f16)0.f;
    } else {
      for (int c = 0; c < 64; c++) lrow[c] = (f16)0.f;
    }
  }
  __syncthreads();
  int wv = tid>>6, lane = tid&63, lg = lane>>4, lr = lane&15;
  // B fragments from W_geo [64 out][56 in], k padded to 64 with zeros
  f16x8 Bf[4][2];
  #pragma unroll
  for (int nt = 0; nt < 4; nt++) {
    #pragma unroll
    for (int ks = 0; ks < 2; ks++) {
      int n = nt*16 + lr;
      int kb = ks*32 + lg*8;
      f16x8 w;
      if (kb < 56) {
        float4 w0 = *(const float4*)(Wgeo + n*56 + kb);
        float4 w1 = *(const float4*)(Wgeo + n*56 + kb + 4);
        w[0]=(f16)w0.x; w[1]=(f16)w0.y; w[2]=(f16)w0.z; w[3]=(f16)w0.w;
        w[4]=(f16)w1.x; w[5]=(f16)w1.y; w[6]=(f16)w1.z; w[7]=(f16)w1.w;
      } else {
        #pragma unroll
        for (int j2 = 0; j2 < 8; j2++) w[j2] = (f16)0.f;
      }
      Bf[nt][ks] = w;
    }
  }
  float ssum[4] = {0,0,0,0}, ssq[4] = {0,0,0,0};
  for (int mt = 0; mt < 4; mt++) {
    int rbase = wv*64 + mt*16;
    f16x8 A0 = *(const f16x8*)(lds + (rbase+lr)*72 + lg*8);
    f16x8 A1 = *(const f16x8*)(lds + (rbase+lr)*72 + 32 + lg*8);
    f32x4 acc[4];
    #pragma unroll
    for (int nt = 0; nt < 4; nt++) { acc[nt][0]=0.f; acc[nt][1]=0.f; acc[nt][2]=0.f; acc[nt][3]=0.f; }
    #pragma unroll
    for (int nt = 0; nt < 4; nt++) {
      acc[nt] = __builtin_amdgcn_mfma_f32_16x16x32_f16(A0, Bf[nt][0], acc[nt], 0, 0, 0);
      acc[nt] = __builtin_amdgcn_mfma_f32_16x16x32_f16(A1, Bf[nt][1], acc[nt], 0, 0, 0);
    }
    #pragma unroll
    for (int nt = 0; nt < 4; nt++) {
      int n = nt*16 + lr;
      float bg = bgeo[n];
      #pragma unroll
      for (int rg = 0; rg < 4; rg++) {
        int rloc = rbase + lg*4 + rg;
        int p = base + rloc;
        bool valid = (p < c0) || (p >= c0p && p < c0p + c1);
        float z = valid ? (acc[nt][rg] + bg) : 0.f;
        ssum[nt] += z; ssq[nt] += z*z;
        lds[rloc*72 + n] = (f16)z;
      }
    }
  }
  #pragma unroll
  for (int nt = 0; nt < 4; nt++) {
    float v = ssum[nt]; v += __shfl_xor(v, 16); v += __shfl_xor(v, 32);
    float w = ssq[nt];  w += __shfl_xor(w, 16); w += __shfl_xor(w, 32);
    if (lane < 16) { atomicAdd(&sstat[nt*16+lane][0], v); atomicAdd(&sstat[nt*16+lane][1], w); }
  }
  __syncthreads();
  {
    int p = base + tid;
    #pragma unroll
    for (int c = 0; c < 8; c++) {
      f16x8 v = *(const f16x8*)(lds + tid*72 + c*8);
      *(f16x8*)(zgeo + (size_t)p*64 + c*8) = v;
    }
  }
  if (tid < 128) {
    float v = ((float*)sstat)[tid];
    if (v != 0.f) atomicAdd(&gstats[(blockIdx.x & (RSTAT-1))*256 + tid], v);
  }
}

// ---------------- interaction layer 0 (K=256), staged gather ----------------
__global__ __launch_bounds__(256) void k_layer0(
    const f16* __restrict__ nfsrc, const f16* __restrict__ zgeo,
    const f16* __restrict__ W0p, const float* __restrict__ b0p,
    const float* __restrict__ g_geo, const float* __restrict__ be_geo,
    const float* __restrict__ geostats, float* __restrict__ outstats,
    const int* __restrict__ sc, const int* __restrict__ ip,
    const int* __restrict__ jp, const int* __restrict__ kp,
    f16* __restrict__ z0)
{
  __shared__ f16 lds[64*264];   // 64 rows x 256 k (+8 pad)
  __shared__ float geoscale[64], geoshift[64];
  __shared__ float sstat[2][64][2];
  int tid = threadIdx.x;
  int c0 = sc[4], c0p = sc[5], c1 = sc[6];
  if (tid < 64) {
    float s = 0.f, sq = 0.f;
    #pragma unroll 8
    for (int r = 0; r < RSTAT; r++) {
      s  += geostats[r*256 + tid*2];
      sq += geostats[r*256 + tid*2 + 1];
    }
    float mean = s * (1.f/(float)E_TRIP);
    float var  = sq * (1.f/(float)E_TRIP) - mean*mean;
    float rstd = rsqrtf(var + EPSF);
    float scl = g_geo[tid]*rstd;
    geoscale[tid] = scl;
    geoshift[tid] = be_geo[tid] - mean*scl;
  }
  ((float*)sstat)[tid] = 0.f;
  __syncthreads();
  int wv = tid>>6, lane = tid&63, lg = lane>>4, lr = lane&15;
  float s0sum[4]={0,0,0,0}, s0sq[4]={0,0,0,0}, s1sum[4]={0,0,0,0}, s1sq[4]={0,0,0,0};
  for (int tile = blockIdx.x; tile < NTILE64; tile += gridDim.x) {
    int rowbase = tile*64;
    int branch = (rowbase >= c0p) ? 1 : 0;
    // phase A: stage xcat tile [64 rows][256 k] in f16
    {
      int r = tid >> 2, q = tid & 3;
      int p = rowbase + r;
      bool valid = (p < c0) || (p >= c0p && p < c0p + c1);
      f16* rowp = lds + r*264 + q*64;
      if (q < 3) {
        if (valid) {
          int idx = (q==0 ? ip : (q==1 ? jp : kp))[p];
          const f16* src = nfsrc + (size_t)idx*64;
          #pragma unroll
          for (int c = 0; c < 8; c++) *(f16x8*)(rowp + c*8) = *(const f16x8*)(src + c*8);
        } else {
          f16x8 u;
          #pragma unroll
          for (int j2 = 0; j2 < 8; j2++) u[j2] = (f16)0.f;
          #pragma unroll
          for (int c = 0; c < 8; c++) *(f16x8*)(rowp + c*8) = u;
        }
      } else {
        if (valid) {
          const f16* zg = zgeo + (size_t)p*64;
          #pragma unroll
          for (int c = 0; c < 8; c++) {
            f16x8 raw = *(const f16x8*)(zg + c*8);
            f16x8 u;
            #pragma unroll
            for (int j2 = 0; j2 < 8; j2++) {
              int f = c*8 + j2;
              float x = fmaxf((float)raw[j2]*geoscale[f] + geoshift[f], 0.f);
              u[j2] = (f16)x;
            }
            *(f16x8*)(rowp + c*8) = u;
          }
        } else {
          f16x8 u;
          #pragma unroll
          for (int j2 = 0; j2 < 8; j2++) u[j2] = (f16)0.f;
          #pragma unroll
          for (int c = 0; c < 8; c++) *(f16x8*)(rowp + c*8) = u;
        }
      }
    }
    __syncthreads();
    // phase B: each wave does 16 rows x 64 cols, K=256
    {
      int r0 = wv*16;
      const f16* Wb = W0p + branch*16384;
      f32x4 acc[4];
      #pragma unroll
      for (int nt = 0; nt < 4; nt++) { acc[nt][0]=0.f; acc[nt][1]=0.f; acc[nt][2]=0.f; acc[nt][3]=0.f; }
      #pragma unroll
      for (int ks = 0; ks < 8; ks++) {
        f16x8 A = *(const f16x8*)(lds + (r0+lr)*264 + (ks*4+lg)*8);
        #pragma unroll
        for (int nt = 0; nt < 4; nt++) {
          f16x8 B = *(const f16x8*)(Wb + (nt*16+lr)*256 + ks*32 + lg*8);
          acc[nt] = __builtin_amdgcn_mfma_f32_16x16x32_f16(A, B, acc[nt], 0, 0, 0);
        }
      }
      #pragma unroll
      for (int nt = 0; nt < 4; nt++) {
        int n = nt*16 + lr;
        float bias = b0p[branch*64 + n];
        #pragma unroll
        for (int rg = 0; rg < 4; rg++) {
          int rloc = r0 + lg*4 + rg;
          int p = rowbase + rloc;
          bool valid = (p < c0) || (p >= c0p && p < c0p + c1);
          float z = valid ? (acc[nt][rg] + bias) : 0.f;
          if (branch == 0) { s0sum[nt] += z; s0sq[nt] += z*z; }
          else             { s1sum[nt] += z; s1sq[nt] += z*z; }
          lds[rloc*264 + n] = (f16)z;
        }
      }
    }
    __syncthreads();
    // store
    {
      int r = tid>>2, q = tid&3;
      int p = rowbase + r;
      f16x8 v0 = *(const f16x8*)(lds + r*264 + q*16);
      f16x8 v1 = *(const f16x8*)(lds + r*264 + q*16 + 8);
      *(f16x8*)(z0 + (size_t)p*64 + q*16) = v0;
      *(f16x8*)(z0 + (size_t)p*64 + q*16 + 8) = v1;
    }
    __syncthreads();
  }
  #pragma unroll
  for (int nt = 0; nt < 4; nt++) {
    float v, w;
    v = s0sum[nt]; v += __shfl_xor(v,16); v += __shfl_xor(v,32);
    w = s0sq[nt];  w += __shfl_xor(w,16); w += __shfl_xor(w,32);
    if (lane < 16) { atomicAdd(&sstat[0][nt*16+lane][0], v); atomicAdd(&sstat[0][nt*16+lane][1], w); }
    v = s1sum[nt]; v += __shfl_xor(v,16); v += __shfl_xor(v,32);
    w = s1sq[nt];  w += __shfl_xor(w,16); w += __shfl_xor(w,32);
    if (lane < 16) { atomicAdd(&sstat[1][nt*16+lane][0], v); atomicAdd(&sstat[1][nt*16+lane][1], w); }
  }
  __syncthreads();
  {
    float v = ((float*)sstat)[tid];
    if (v != 0.f) atomicAdd(&outstats[(blockIdx.x & (RSTAT-1))*256 + tid], v);
  }
}

// ---------------- hidden layers (K=64) ----------------
__global__ __launch_bounds__(256) void k_hidden(
    const f16* __restrict__ zin, f16* __restrict__ zout,
    const f16* __restrict__ Wp, const float* __restrict__ biasp,
    const float* __restrict__ bngp, const float* __restrict__ bnbp,
    const float* __restrict__ instats, float* __restrict__ outstats,
    const int* __restrict__ sc)
{
  __shared__ float lscale[2][64], lshift[2][64];
  __shared__ float sstat[2][64][2];
  __shared__ f16 ldso[4][16*72];
  int tid = threadIdx.x;
  int c0 = sc[4], c0p = sc[5], c1 = sc[6];
  if (tid < 128) {
    int b = tid>>6, n = tid&63;
    int cb = b ? c1 : c0; if (cb < 1) cb = 1;
    float inv = 1.f/(float)cb;
    int idx = (b*64+n)*2;
    float s = 0.f, sq = 0.f;
    #pragma unroll 8
    for (int r = 0; r < RSTAT; r++) {
      s  += instats[r*256 + idx];
      sq += instats[r*256 + idx + 1];
    }
    float mean = s*inv, var = sq*inv - mean*mean;
    float rstd = rsqrtf(var + EPSF);
    float scl = bngp[b*256+n]*rstd;
    lscale[b][n] = scl;
    lshift[b][n] = bnbp[b*256+n] - mean*scl;
  }
  ((float*)sstat)[tid] = 0.f;
  __syncthreads();
  int wv = tid>>6, lane = tid&63, lg = lane>>4, lr = lane&15;
  f16* myldso = ldso[wv];
  float s0sum[4]={0,0,0,0}, s0sq[4]={0,0,0,0}, s1sum[4]={0,0,0,0}, s1sq[4]={0,0,0,0};
  for (int tile = blockIdx.x; tile < NTILE64; tile += gridDim.x) {
    int rowbase = tile*64;
    int branch = (rowbase >= c0p) ? 1 : 0;
    int rgl = rowbase + wv*16 + lr;
    f16x8 Af[2];
    #pragma unroll
    for (int ks = 0; ks < 2; ks++) {
      f16x8 raw = *(const f16x8*)(zin + (size_t)rgl*64 + ks*32 + lg*8);
      f16x8 A;
      #pragma unroll
      for (int j2 = 0; j2 < 8; j2++) {
        int f = ks*32 + lg*8 + j2;
        float x = fmaxf((float)raw[j2]*lscale[branch][f] + lshift[branch][f], 0.f);
        A[j2] = (f16)x;
      }
      Af[ks] = A;
    }
    f32x4 acc[4];
    #pragma unroll
    for (int nt = 0; nt < 4; nt++) { acc[nt][0]=0.f; acc[nt][1]=0.f; acc[nt][2]=0.f; acc[nt][3]=0.f; }
    #pragma unroll
    for (int ks = 0; ks < 2; ks++) {
      #pragma unroll
      for (int nt = 0; nt < 4; nt++) {
        f16x8 B = *(const f16x8*)(Wp + branch*12288 + (nt*16+lr)*64 + ks*32 + lg*8);
        acc[nt] = __builtin_amdgcn_mfma_f32_16x16x32_f16(Af[ks], B, acc[nt], 0, 0, 0);
      }
    }
    #pragma unroll
    for (int nt = 0; nt < 4; nt++) {
      int n = nt*16 + lr;
      float bias = biasp[branch*192 + n];
      #pragma unroll
      for (int rg = 0; rg < 4; rg++) {
        int rloc = lg*4 + rg;
        int p = rowbase + wv*16 + rloc;
        bool valid = (p < c0) || (p >= c0p && p < c0p + c1);
        float z = valid ? (acc[nt][rg] + bias) : 0.f;
        if (branch == 0) { s0sum[nt] += z; s0sq[nt] += z*z; }
        else             { s1sum[nt] += z; s1sq[nt] += z*z; }
        myldso[rloc*72 + n] = (f16)z;
      }
    }
    {
      int r2 = lane>>2, q = lane&3;
      int p2 = rowbase + wv*16 + r2;
      f16x8 v0 = *(const f16x8*)(myldso + r2*72 + q*8);
      f16x8 v1 = *(const f16x8*)(myldso + r2*72 + 32 + q*8);
      *(f16x8*)(zout + (size_t)p2*64 + q*8) = v0;
      *(f16x8*)(zout + (size_t)p2*64 + 32 + q*8) = v1;
    }
  }
  #pragma unroll
  for (int nt = 0; nt < 4; nt++) {
    float v, w;
    v = s0sum[nt]; v += __shfl_xor(v,16); v += __shfl_xor(v,32);
    w = s0sq[nt];  w += __shfl_xor(w,16); w += __shfl_xor(w,32);
    if (lane < 16) { atomicAdd(&sstat[0][nt*16+lane][0], v); atomicAdd(&sstat[0][nt*16+lane][1], w); }
    v = s1sum[nt]; v += __shfl_xor(v,16); v += __shfl_xor(v,32);
    w = s1sq[nt];  w += __shfl_xor(w,16); w += __shfl_xor(w,32);
    if (lane < 16) { atomicAdd(&sstat[1][nt*16+lane][0], v); atomicAdd(&sstat[1][nt*16+lane][1], w); }
  }
  __syncthreads();
  {
    float v = ((float*)sstat)[tid];
    if (v != 0.f) atomicAdd(&outstats[(blockIdx.x & (RSTAT-1))*256 + tid], v);
  }
}

// ---------------- final BN + relu + att + destination-sorted segment sum ----------------
__global__ __launch_bounds__(256) void k_scatter(
    const f16* __restrict__ z3, const float* __restrict__ att,
    const float* __restrict__ bngp, const float* __restrict__ bnbp,
    const float* __restrict__ instats, const int* __restrict__ sc,
    const int* __restrict__ start, const int* __restrict__ dperm,
    float* __restrict__ outt, f16* __restrict__ nfh)
{
  __shared__ float lscale[2][64], lshift[2][64];
  int tid = threadIdx.x;
  int c0p = sc[5];
  {
    int c0 = sc[4], c1 = sc[6];
    if (tid < 128) {
      int b = tid>>6, n = tid&63;
      int cb = b ? c1 : c0; if (cb < 1) cb = 1;
      float inv = 1.f/(float)cb;
      int idx = (b*64+n)*2;
      float s = 0.f, sq = 0.f;
      #pragma unroll 8
      for (int r = 0; r < RSTAT; r++) {
        s  += instats[r*256 + idx];
        sq += instats[r*256 + idx + 1];
      }
      float mean = s*inv, var = sq*inv - mean*mean;
      float rstd = rsqrtf(var + EPSF);
      float scl = bngp[b*256+n]*rstd;
      lscale[b][n] = scl;
      lshift[b][n] = bnbp[b*256+n] - mean*scl;
    }
  }
  __syncthreads();
  int gid = blockIdx.x*256 + tid;
  int n = gid >> 3, q = gid & 7;
  if (n >= NN) return;
  int s = start[n];
  int e = start[n+1];
  float a0 = att[0], a1 = att[1];
  float acc[8] = {0,0,0,0,0,0,0,0};
  float sc0[8], sh0[8], sc1[8], sh1[8];
  #pragma unroll
  for (int j2 = 0; j2 < 8; j2++) {
    int f = q*8 + j2;
    sc0[j2] = lscale[0][f]; sh0[j2] = lshift[0][f];
    sc1[j2] = lscale[1][f]; sh1[j2] = lshift[1][f];
  }
  for (int t = s; t < e; t++) {
    int p = dperm[t];
    int b = (p >= c0p) ? 1 : 0;
    float a = b ? a1 : a0;
    f16x8 raw = *(const f16x8*)(z3 + (size_t)p*64 + q*8);
    #pragma unroll
    for (int j2 = 0; j2 < 8; j2++) {
      float x = (float)raw[j2]*(b ? sc1[j2] : sc0[j2]) + (b ? sh1[j2] : sh0[j2]);
      acc[j2] += fmaxf(x, 0.f) * a;   // leaky_relu identity for x>=0
    }
  }
  float4 lo, hi;
  lo.x=acc[0]; lo.y=acc[1]; lo.z=acc[2]; lo.w=acc[3];
  hi.x=acc[4]; hi.y=acc[5]; hi.z=acc[6]; hi.w=acc[7];
  *(float4*)(outt + (size_t)n*64 + q*8) = lo;
  *(float4*)(outt + (size_t)n*64 + q*8 + 4) = hi;
  f16x8 h;
  #pragma unroll
  for (int j2 = 0; j2 < 8; j2++) h[j2] = (f16)acc[j2];
  *(f16x8*)(nfh + (size_t)n*64 + q*8) = h;
}

extern "C" void kernel_launch(void* const* d_in, const int* in_sizes, int n_in,
                              void* d_out, int out_size, void* d_ws, size_t ws_size,
                              hipStream_t stream)
{
  const float* input_feature = (const float*)d_in[0];
  const float* coords   = (const float*)d_in[1];
  const float* face_x   = (const float*)d_in[3];
  const float* att      = (const float*)d_in[4];
  const float* W_geo    = (const float*)d_in[5];
  const float* b_geo    = (const float*)d_in[6];
  const float* g_geo    = (const float*)d_in[7];
  const float* be_geo   = (const float*)d_in[8];
  const float* spnn_W0  = (const float*)d_in[9];
  const float* spnn_b0  = (const float*)d_in[10];
  const float* spnn_Wr  = (const float*)d_in[11];
  const float* spnn_br  = (const float*)d_in[12];
  const float* bn_g     = (const float*)d_in[13];
  const float* bn_b     = (const float*)d_in[14];
  const int* ewf  = (const int*)d_in[15];
  const int* eidx = (const int*)d_in[16];
  const int* exjk = (const int*)d_in[17];
  const int* exij = (const int*)d_in[18];
  float* out = (float*)d_out;
  char* ws = (char*)d_ws;

  size_t off = 0;
  auto take = [&](size_t bytes) -> char* {
    size_t o = off; off = (off + bytes + 255) & ~(size_t)255; return ws + o;
  };
  const size_t STATBUF = (size_t)RSTAT*256;           // floats per stat buffer
  int*   sc     = (int*)take(256);
  float* stats  = (float*)take(13*STATBUF*sizeof(float));  // geo + 3*4 layer stat buffers, replicated
  int*   cb0    = (int*)take(sizeof(int)*2048);
  int*   base0  = (int*)take(sizeof(int)*2048);
  int*   base1  = (int*)take(sizeof(int)*2048);
  int*   cnt    = (int*)take(sizeof(int)*NN);
  int*   startn = (int*)take(sizeof(int)*(NN+1));
  int*   curn   = (int*)take(sizeof(int)*NN);
  int*   btot   = (int*)take(sizeof(int)*256);
  int*   dperm  = (int*)take(sizeof(int)*EPAD);
  unsigned char* biedge = (unsigned char*)take(E_TRIP);
  int* epos = (int*)take(sizeof(int)*EPAD);
  int* ip   = (int*)take(sizeof(int)*EPAD);
  int* jp   = (int*)take(sizeof(int)*EPAD);
  int* kp   = (int*)take(sizeof(int)*EPAD);
  f16* W0h  = (f16*)take(sizeof(f16)*3*2*64*256);
  f16* Wrh  = (f16*)take(sizeof(f16)*3*2*3*64*64);
  f16* nf16 = (f16*)take(sizeof(f16)*(size_t)NN*64);
  f16* zgeo = (f16*)take(sizeof(f16)*(size_t)EPAD*64);
  f16* zA   = (f16*)take(sizeof(f16)*(size_t)EPAD*64);
  f16* zB   = (f16*)take(sizeof(f16)*(size_t)EPAD*64);
  if (off > ws_size) return;  // workspace insufficient; cannot run

  hipMemsetAsync(sc, 0, 256, stream);
  hipMemsetAsync(stats, 0, 13*STATBUF*sizeof(float), stream);
  hipMemsetAsync(cnt, 0, sizeof(int)*NN, stream);

  k_count    <<<NBLK, 256, 0, stream>>>(ewf, exij, exjk, biedge, cb0);
  k_scanb    <<<1, 1024, 0, stream>>>(cb0, base0, base1, sc);
  k_partition<<<NBLK, 256, 0, stream>>>(biedge, eidx, base0, base1, epos, ip, jp, kp);
  k_cvt      <<<25673, 256, 0, stream>>>(spnn_W0, spnn_Wr, input_feature, W0h, Wrh, nf16);
  // destination counting sort (i is the same for all 3 interactions)
  k_hist <<<1954, 256, 0, stream>>>(ip, sc, cnt);
  k_scan1<<<196, 512, 0, stream>>>(cnt, startn, btot);
  k_scan2<<<1, 256, 0, stream>>>(btot);
  k_scan3<<<196, 512, 0, stream>>>(startn, curn, btot, sc);
  k_place<<<1954, 256, 0, stream>>>(ip, sc, curn, dperm);

  k_geo      <<<NBLK256, 256, 0, stream>>>(coords, face_x, ewf, exij, exjk, W_geo, b_geo,
                                           sc, epos, ip, jp, kp, zgeo, stats);
  for (int t = 0; t < 3; t++) {
    float* outt = out + (size_t)t*NN*64;
    k_layer0<<<1024, 256, 0, stream>>>(nf16, zgeo,
        W0h + (size_t)t*2*64*256, spnn_b0 + t*2*64,
        g_geo, be_geo, stats, stats + (size_t)(1 + t*4)*STATBUF,
        sc, ip, jp, kp, zA);
    f16* zi = zA; f16* zo = zB;
    for (int h = 0; h < 3; h++) {
      k_hidden<<<2048, 256, 0, stream>>>(zi, zo,
          Wrh + (size_t)t*2*3*64*64 + (size_t)h*64*64,
          spnn_br + t*2*3*64 + h*64,
          bn_g + t*2*4*64 + h*64,
          bn_b + t*2*4*64 + h*64,
          stats + (size_t)(1 + t*4 + h)*STATBUF,
          stats + (size_t)(1 + t*4 + h + 1)*STATBUF,
          sc);
      f16* tmp = zi; zi = zo; zo = tmp;
    }
    k_scatter<<<(NN*8 + 255)/256, 256, 0, stream>>>(zi, att,
        bn_g + t*2*4*64 + 3*64, bn_b + t*2*4*64 + 3*64,
        stats + (size_t)(1 + t*4 + 3)*STATBUF, sc, startn, dperm, outt, nf16);
  }
}

// Round 10
// 1386.035 us; speedup vs baseline: 3.8086x; 1.0004x over previous
//
#include <hip/hip_runtime.h>

#define E_TRIP 500000
#define EPAD   500224              // multiple of 256; >= c0_pad + c1 always
#define NTILE64 (EPAD/64)          // 7816
#define NBLK256 (EPAD/256)         // 1954
#define NBLK    1954               // edge blocks (256 edges each)
#define NN 100000
#define NBIN (2*NN)                // counting-sort bins: branch*NN + i
#define EPSF 1e-5f
#define RSTAT 64                   // stats replication factor (kills atomic tail contention)

typedef _Float16 f16;
typedef _Float16 f16x8 __attribute__((ext_vector_type(8)));
typedef float f32x4 __attribute__((ext_vector_type(4)));

// ---------------- prep: per-block branch counts (no global atomics) ----------------
__global__ __launch_bounds__(256) void k_count(const int* __restrict__ ewf,
    const int* __restrict__ exij, const int* __restrict__ exjk,
    unsigned char* __restrict__ biedge, int* __restrict__ cb0)
{
  __shared__ int wcnt[4];
  int e = blockIdx.x*256 + threadIdx.x;
  bool active = e < E_TRIP;
  int b = 0;
  if (active) {
    int fij = ewf[exij[e]];
    int fjk = ewf[exjk[e]];
    b = (fij == fjk) ? 0 : 1;
    biedge[e] = (unsigned char)b;
  }
  unsigned long long m0 = __ballot(active && b==0);
  int lane = threadIdx.x & 63, wv = threadIdx.x >> 6;
  if (lane == 0) wcnt[wv] = (int)__popcll(m0);
  __syncthreads();
  if (threadIdx.x == 0) cb0[blockIdx.x] = wcnt[0] + wcnt[1] + wcnt[2] + wcnt[3];
}

// single block: scan per-block counts -> c0/c0p/c1
__global__ __launch_bounds__(1024) void k_scanb(const int* __restrict__ cb0, int* __restrict__ sc)
{
  __shared__ int s[2048];
  int tid = threadIdx.x;
  int i0 = tid, i1 = tid + 1024;
  s[i0] = (i0 < NBLK) ? cb0[i0] : 0;
  s[i1] = (i1 < NBLK) ? cb0[i1] : 0;
  __syncthreads();
  for (int off = 1; off < 2048; off <<= 1) {
    int v0 = (i0 >= off) ? s[i0 - off] : 0;
    int v1 = (i1 >= off) ? s[i1 - off] : 0;
    __syncthreads();
    s[i0] += v0; s[i1] += v1;
    __syncthreads();
  }
  if (tid == 0) {
    int c0 = s[NBLK-1];
    int c0p = (c0 + 63) & ~63;
    sc[4] = c0; sc[5] = c0p; sc[6] = E_TRIP - c0;
  }
}

__global__ __launch_bounds__(256) void k_cvt(const float* __restrict__ W0,
    const float* __restrict__ Wr, const float* __restrict__ nf,
    f16* __restrict__ W0h, f16* __restrict__ Wrh, f16* __restrict__ nfh)
{
  int i = (blockIdx.x*256 + threadIdx.x) * 4;
  if (i < 98304) {
    float4 v = *(const float4*)(W0 + i);
    W0h[i]=(f16)v.x; W0h[i+1]=(f16)v.y; W0h[i+2]=(f16)v.z; W0h[i+3]=(f16)v.w;
  } else if (i < 172032) {
    int j = i - 98304;
    float4 v = *(const float4*)(Wr + j);
    Wrh[j]=(f16)v.x; Wrh[j+1]=(f16)v.y; Wrh[j+2]=(f16)v.z; Wrh[j+3]=(f16)v.w;
  } else {
    int j = i - 172032;
    if (j < NN*64) {
      float4 v = *(const float4*)(nf + j);
      nfh[j]=(f16)v.x; nfh[j+1]=(f16)v.y; nfh[j+2]=(f16)v.z; nfh[j+3]=(f16)v.w;
    }
  }
}

// ---- counting sort by key = branch*NN + i  (positions sorted by i within branch) ----
__global__ __launch_bounds__(256) void k_hist(const unsigned char* __restrict__ biedge,
    const int* __restrict__ eidx, int* __restrict__ cnt)
{
  int e = blockIdx.x*256 + threadIdx.x;
  if (e < E_TRIP) {
    int key = (int)biedge[e]*NN + eidx[e];
    atomicAdd(&cnt[key], 1);
  }
}

__global__ __launch_bounds__(512) void k_scan1(const int* __restrict__ cnt,
    int* __restrict__ start, int* __restrict__ btot)
{
  __shared__ int s[512];
  int tid = threadIdx.x;
  int g = blockIdx.x*512 + tid;
  int x = (g < NBIN) ? cnt[g] : 0;
  s[tid] = x; __syncthreads();
  #pragma unroll
  for (int off = 1; off < 512; off <<= 1) {
    int v = (tid >= off) ? s[tid-off] : 0;
    __syncthreads();
    s[tid] += v;
    __syncthreads();
  }
  if (g < NBIN) start[g] = s[tid] - x;   // exclusive within chunk
  if (tid == 511) btot[blockIdx.x] = s[511];
}

__global__ __launch_bounds__(512) void k_scan2(int* __restrict__ btot)
{
  __shared__ int s[512];
  int tid = threadIdx.x;
  int x = (tid < 391) ? btot[tid] : 0;
  s[tid] = x; __syncthreads();
  #pragma unroll
  for (int off = 1; off < 512; off <<= 1) {
    int v = (tid >= off) ? s[tid-off] : 0;
    __syncthreads();
    s[tid] += v;
    __syncthreads();
  }
  if (tid < 391) btot[tid] = s[tid] - x;  // exclusive
}

__global__ __launch_bounds__(512) void k_scan3(int* __restrict__ start,
    int* __restrict__ cur, const int* __restrict__ btot, const int* __restrict__ sc)
{
  int tid = threadIdx.x;
  int g = blockIdx.x*512 + tid;
  if (g < NBIN) {
    int v = start[g] + btot[blockIdx.x];
    if (g >= NN) v += sc[5] - sc[4];     // branch1 segment starts at c0p
    start[g] = v;
    cur[g] = v;
  }
  if (g == 0) start[NBIN] = sc[5] + sc[6];
}

__global__ __launch_bounds__(256) void k_place(const unsigned char* __restrict__ biedge,
    const int* __restrict__ eidx, int* __restrict__ cur,
    int* __restrict__ epos, int* __restrict__ ip, int* __restrict__ jp, int* __restrict__ kp)
{
  int e = blockIdx.x*256 + threadIdx.x;
  if (e < E_TRIP) {
    int i = eidx[e];
    int key = (int)biedge[e]*NN + i;
    int pos = atomicAdd(&cur[key], 1);
    epos[pos] = e;
    ip[pos] = i;
    jp[pos] = eidx[E_TRIP + e];
    kp[pos] = eidx[2*E_TRIP + e];
  }
}

// ---------------- geo MLP input layer ----------------
__global__ __launch_bounds__(256) void k_geo(
    const float* __restrict__ coords, const float* __restrict__ facex,
    const int* __restrict__ ewf, const int* __restrict__ exij, const int* __restrict__ exjk,
    const float* __restrict__ Wgeo, const float* __restrict__ bgeo,
    const int* __restrict__ sc, const int* __restrict__ epos,
    const int* __restrict__ ip, const int* __restrict__ jp, const int* __restrict__ kp,
    f16* __restrict__ zgeo, float* __restrict__ gstats)
{
  __shared__ f16 lds[256*72];         // 256 rows x 64 feats (+8 pad) f16
  __shared__ float sstat[64][2];
  int tid = threadIdx.x;
  int base = blockIdx.x*256;
  int c0 = sc[4], c0p = sc[5], c1 = sc[6];
  if (tid < 128) ((float*)sstat)[tid] = 0.f;
  {
    int p = base + tid;
    bool valid = (p < c0) || (p >= c0p && p < c0p + c1);
    f16* lrow = lds + tid*72;
    if (valid) {
      int e = epos[p];
      int ii = ip[p], jj = jp[p], kk = kp[p];
      float cix = coords[ii*3+0], ciy = coords[ii*3+1], ciz = coords[ii*3+2];
      float cjx = coords[jj*3+0], cjy = coords[jj*3+1], cjz = coords[jj*3+2];
      float ckx = coords[kk*3+0], cky = coords[kk*3+1], ckz = coords[kk*3+2];
      float v1x = cjx-cix, v1y = cjy-ciy, v1z = cjz-ciz;
      float v2x = ckx-cjx, v2y = cky-cjy, v2z = ckz-cjz;
      float dij = sqrtf(v1x*v1x + v1y*v1y + v1z*v1z);
      float djk = sqrtf(v2x*v2x + v2y*v2y + v2z*v2z);
      float cx = v1y*v2z - v1z*v2y;
      float cy = v1z*v2x - v1x*v2z;
      float cz = v1x*v2y - v1y*v2x;
      float theta = atan2f(sqrtf(cx*cx+cy*cy+cz*cz), v1x*v2x+v1y*v2y+v1z*v2z);
      lrow[0]=(f16)dij; lrow[1]=(f16)djk; lrow[2]=(f16)theta; lrow[3]=(f16)0.f;
      lrow[4]=(f16)cjx; lrow[5]=(f16)cjy; lrow[6]=(f16)cjz;
      lrow[7]=(f16)cix; lrow[8]=(f16)ciy; lrow[9]=(f16)ciz;
      int fij = ewf[exij[e]], fjk = ewf[exjk[e]];
      const float* fx1 = facex + (size_t)fij*23;
      const float* fx2 = facex + (size_t)fjk*23;
      for (int c = 0; c < 23; c++) lrow[10+c] = (f16)fx1[c];
      for (int c = 0; c < 23; c++) lrow[33+c] = (f16)fx2[c];
      for (int c = 56; c < 64; c++) lrow[c] = (f16)0.f;
    } else {
      for (int c = 0; c < 64; c++) lrow[c] = (f16)0.f;
    }
  }
  __syncthreads();
  int wv = tid>>6, lane = tid&63, lg = lane>>4, lr = lane&15;
  f16x8 Bf[4][2];
  #pragma unroll
  for (int nt = 0; nt < 4; nt++) {
    #pragma unroll
    for (int ks = 0; ks < 2; ks++) {
      int n = nt*16 + lr;
      int kb = ks*32 + lg*8;
      f16x8 w;
      if (kb < 56) {
        float4 w0 = *(const float4*)(Wgeo + n*56 + kb);
        float4 w1 = *(const float4*)(Wgeo + n*56 + kb + 4);
        w[0]=(f16)w0.x; w[1]=(f16)w0.y; w[2]=(f16)w0.z; w[3]=(f16)w0.w;
        w[4]=(f16)w1.x; w[5]=(f16)w1.y; w[6]=(f16)w1.z; w[7]=(f16)w1.w;
      } else {
        #pragma unroll
        for (int j2 = 0; j2 < 8; j2++) w[j2] = (f16)0.f;
      }
      Bf[nt][ks] = w;
    }
  }
  float ssum[4] = {0,0,0,0}, ssq[4] = {0,0,0,0};
  for (int mt = 0; mt < 4; mt++) {
    int rbase = wv*64 + mt*16;
    f16x8 A0 = *(const f16x8*)(lds + (rbase+lr)*72 + lg*8);
    f16x8 A1 = *(const f16x8*)(lds + (rbase+lr)*72 + 32 + lg*8);
    f32x4 acc[4];
    #pragma unroll
    for (int nt = 0; nt < 4; nt++) { acc[nt][0]=0.f; acc[nt][1]=0.f; acc[nt][2]=0.f; acc[nt][3]=0.f; }
    #pragma unroll
    for (int nt = 0; nt < 4; nt++) {
      acc[nt] = __builtin_amdgcn_mfma_f32_16x16x32_f16(A0, Bf[nt][0], acc[nt], 0, 0, 0);
      acc[nt] = __builtin_amdgcn_mfma_f32_16x16x32_f16(A1, Bf[nt][1], acc[nt], 0, 0, 0);
    }
    #pragma unroll
    for (int nt = 0; nt < 4; nt++) {
      int n = nt*16 + lr;
      float bg = bgeo[n];
      #pragma unroll
      for (int rg = 0; rg < 4; rg++) {
        int rloc = rbase + lg*4 + rg;
        int p = base + rloc;
        bool valid = (p < c0) || (p >= c0p && p < c0p + c1);
        float z = valid ? (acc[nt][rg] + bg) : 0.f;
        ssum[nt] += z; ssq[nt] += z*z;
        lds[rloc*72 + n] = (f16)z;
      }
    }
  }
  #pragma unroll
  for (int nt = 0; nt < 4; nt++) {
    float v = ssum[nt]; v += __shfl_xor(v, 16); v += __shfl_xor(v, 32);
    float w = ssq[nt];  w += __shfl_xor(w, 16); w += __shfl_xor(w, 32);
    if (lane < 16) { atomicAdd(&sstat[nt*16+lane][0], v); atomicAdd(&sstat[nt*16+lane][1], w); }
  }
  __syncthreads();
  {
    int p = base + tid;
    #pragma unroll
    for (int c = 0; c < 8; c++) {
      f16x8 v = *(const f16x8*)(lds + tid*72 + c*8);
      *(f16x8*)(zgeo + (size_t)p*64 + c*8) = v;
    }
  }
  if (tid < 128) {
    float v = ((float*)sstat)[tid];
    if (v != 0.f) atomicAdd(&gstats[(blockIdx.x & (RSTAT-1))*256 + tid], v);
  }
}

// ---------------- interaction layer 0 (K=256), staged gather ----------------
__global__ __launch_bounds__(256) void k_layer0(
    const f16* __restrict__ nfsrc, const f16* __restrict__ zgeo,
    const f16* __restrict__ W0p, const float* __restrict__ b0p,
    const float* __restrict__ g_geo, const float* __restrict__ be_geo,
    const float* __restrict__ geostats, float* __restrict__ outstats,
    const int* __restrict__ sc, const int* __restrict__ ip,
    const int* __restrict__ jp, const int* __restrict__ kp,
    f16* __restrict__ z0)
{
  __shared__ f16 lds[64*264];   // 64 rows x 256 k (+8 pad)
  __shared__ float geoscale[64], geoshift[64];
  __shared__ float sstat[2][64][2];
  int tid = threadIdx.x;
  int c0 = sc[4], c0p = sc[5], c1 = sc[6];
  if (tid < 64) {
    float s = 0.f, sq = 0.f;
    #pragma unroll 8
    for (int r = 0; r < RSTAT; r++) {
      s  += geostats[r*256 + tid*2];
      sq += geostats[r*256 + tid*2 + 1];
    }
    float mean = s * (1.f/(float)E_TRIP);
    float var  = sq * (1.f/(float)E_TRIP) - mean*mean;
    float rstd = rsqrtf(var + EPSF);
    float scl = g_geo[tid]*rstd;
    geoscale[tid] = scl;
    geoshift[tid] = be_geo[tid] - mean*scl;
  }
  ((float*)sstat)[tid] = 0.f;
  __syncthreads();
  int wv = tid>>6, lane = tid&63, lg = lane>>4, lr = lane&15;
  float s0sum[4]={0,0,0,0}, s0sq[4]={0,0,0,0}, s1sum[4]={0,0,0,0}, s1sq[4]={0,0,0,0};
  for (int tile = blockIdx.x; tile < NTILE64; tile += gridDim.x) {
    int rowbase = tile*64;
    int branch = (rowbase >= c0p) ? 1 : 0;
    {
      int r = tid >> 2, q = tid & 3;
      int p = rowbase + r;
      bool valid = (p < c0) || (p >= c0p && p < c0p + c1);
      f16* rowp = lds + r*264 + q*64;
      if (q < 3) {
        if (valid) {
          int idx = (q==0 ? ip : (q==1 ? jp : kp))[p];
          const f16* src = nfsrc + (size_t)idx*64;
          #pragma unroll
          for (int c = 0; c < 8; c++) *(f16x8*)(rowp + c*8) = *(const f16x8*)(src + c*8);
        } else {
          f16x8 u;
          #pragma unroll
          for (int j2 = 0; j2 < 8; j2++) u[j2] = (f16)0.f;
          #pragma unroll
          for (int c = 0; c < 8; c++) *(f16x8*)(rowp + c*8) = u;
        }
      } else {
        if (valid) {
          const f16* zg = zgeo + (size_t)p*64;
          #pragma unroll
          for (int c = 0; c < 8; c++) {
            f16x8 raw = *(const f16x8*)(zg + c*8);
            f16x8 u;
            #pragma unroll
            for (int j2 = 0; j2 < 8; j2++) {
              int f = c*8 + j2;
              float x = fmaxf((float)raw[j2]*geoscale[f] + geoshift[f], 0.f);
              u[j2] = (f16)x;
            }
            *(f16x8*)(rowp + c*8) = u;
          }
        } else {
          f16x8 u;
          #pragma unroll
          for (int j2 = 0; j2 < 8; j2++) u[j2] = (f16)0.f;
          #pragma unroll
          for (int c = 0; c < 8; c++) *(f16x8*)(rowp + c*8) = u;
        }
      }
    }
    __syncthreads();
    {
      int r0 = wv*16;
      const f16* Wb = W0p + branch*16384;
      f32x4 acc[4];
      #pragma unroll
      for (int nt = 0; nt < 4; nt++) { acc[nt][0]=0.f; acc[nt][1]=0.f; acc[nt][2]=0.f; acc[nt][3]=0.f; }
      #pragma unroll
      for (int ks = 0; ks < 8; ks++) {
        f16x8 A = *(const f16x8*)(lds + (r0+lr)*264 + (ks*4+lg)*8);
        #pragma unroll
        for (int nt = 0; nt < 4; nt++) {
          f16x8 B = *(const f16x8*)(Wb + (nt*16+lr)*256 + ks*32 + lg*8);
          acc[nt] = __builtin_amdgcn_mfma_f32_16x16x32_f16(A, B, acc[nt], 0, 0, 0);
        }
      }
      #pragma unroll
      for (int nt = 0; nt < 4; nt++) {
        int n = nt*16 + lr;
        float bias = b0p[branch*64 + n];
        #pragma unroll
        for (int rg = 0; rg < 4; rg++) {
          int rloc = r0 + lg*4 + rg;
          int p = rowbase + rloc;
          bool valid = (p < c0) || (p >= c0p && p < c0p + c1);
          float z = valid ? (acc[nt][rg] + bias) : 0.f;
          if (branch == 0) { s0sum[nt] += z; s0sq[nt] += z*z; }
          else             { s1sum[nt] += z; s1sq[nt] += z*z; }
          lds[rloc*264 + n] = (f16)z;
        }
      }
    }
    __syncthreads();
    {
      int r = tid>>2, q = tid&3;
      int p = rowbase + r;
      f16x8 v0 = *(const f16x8*)(lds + r*264 + q*16);
      f16x8 v1 = *(const f16x8*)(lds + r*264 + q*16 + 8);
      *(f16x8*)(z0 + (size_t)p*64 + q*16) = v0;
      *(f16x8*)(z0 + (size_t)p*64 + q*16 + 8) = v1;
    }
    __syncthreads();
  }
  #pragma unroll
  for (int nt = 0; nt < 4; nt++) {
    float v, w;
    v = s0sum[nt]; v += __shfl_xor(v,16); v += __shfl_xor(v,32);
    w = s0sq[nt];  w += __shfl_xor(w,16); w += __shfl_xor(w,32);
    if (lane < 16) { atomicAdd(&sstat[0][nt*16+lane][0], v); atomicAdd(&sstat[0][nt*16+lane][1], w); }
    v = s1sum[nt]; v += __shfl_xor(v,16); v += __shfl_xor(v,32);
    w = s1sq[nt];  w += __shfl_xor(w,16); w += __shfl_xor(w,32);
    if (lane < 16) { atomicAdd(&sstat[1][nt*16+lane][0], v); atomicAdd(&sstat[1][nt*16+lane][1], w); }
  }
  __syncthreads();
  {
    float v = ((float*)sstat)[tid];
    if (v != 0.f) atomicAdd(&outstats[(blockIdx.x & (RSTAT-1))*256 + tid], v);
  }
}

// ---------------- hidden layers (K=64) ----------------
__global__ __launch_bounds__(256) void k_hidden(
    const f16* __restrict__ zin, f16* __restrict__ zout,
    const f16* __restrict__ Wp, const float* __restrict__ biasp,
    const float* __restrict__ bngp, const float* __restrict__ bnbp,
    const float* __restrict__ instats, float* __restrict__ outstats,
    const int* __restrict__ sc)
{
  __shared__ float lscale[2][64], lshift[2][64];
  __shared__ float sstat[2][64][2];
  __shared__ f16 ldso[4][16*72];
  int tid = threadIdx.x;
  int c0 = sc[4], c0p = sc[5], c1 = sc[6];
  if (tid < 128) {
    int b = tid>>6, n = tid&63;
    int cb = b ? c1 : c0; if (cb < 1) cb = 1;
    float inv = 1.f/(float)cb;
    int idx = (b*64+n)*2;
    float s = 0.f, sq = 0.f;
    #pragma unroll 8
    for (int r = 0; r < RSTAT; r++) {
      s  += instats[r*256 + idx];
      sq += instats[r*256 + idx + 1];
    }
    float mean = s*inv, var = sq*inv - mean*mean;
    float rstd = rsqrtf(var + EPSF);
    float scl = bngp[b*256+n]*rstd;
    lscale[b][n] = scl;
    lshift[b][n] = bnbp[b*256+n] - mean*scl;
  }
  ((float*)sstat)[tid] = 0.f;
  __syncthreads();
  int wv = tid>>6, lane = tid&63, lg = lane>>4, lr = lane&15;
  f16* myldso = ldso[wv];
  float s0sum[4]={0,0,0,0}, s0sq[4]={0,0,0,0}, s1sum[4]={0,0,0,0}, s1sq[4]={0,0,0,0};
  for (int tile = blockIdx.x; tile < NTILE64; tile += gridDim.x) {
    int rowbase = tile*64;
    int branch = (rowbase >= c0p) ? 1 : 0;
    int rgl = rowbase + wv*16 + lr;
    f16x8 Af[2];
    #pragma unroll
    for (int ks = 0; ks < 2; ks++) {
      f16x8 raw = *(const f16x8*)(zin + (size_t)rgl*64 + ks*32 + lg*8);
      f16x8 A;
      #pragma unroll
      for (int j2 = 0; j2 < 8; j2++) {
        int f = ks*32 + lg*8 + j2;
        float x = fmaxf((float)raw[j2]*lscale[branch][f] + lshift[branch][f], 0.f);
        A[j2] = (f16)x;
      }
      Af[ks] = A;
    }
    f32x4 acc[4];
    #pragma unroll
    for (int nt = 0; nt < 4; nt++) { acc[nt][0]=0.f; acc[nt][1]=0.f; acc[nt][2]=0.f; acc[nt][3]=0.f; }
    #pragma unroll
    for (int ks = 0; ks < 2; ks++) {
      #pragma unroll
      for (int nt = 0; nt < 4; nt++) {
        f16x8 B = *(const f16x8*)(Wp + branch*12288 + (nt*16+lr)*64 + ks*32 + lg*8);
        acc[nt] = __builtin_amdgcn_mfma_f32_16x16x32_f16(Af[ks], B, acc[nt], 0, 0, 0);
      }
    }
    #pragma unroll
    for (int nt = 0; nt < 4; nt++) {
      int n = nt*16 + lr;
      float bias = biasp[branch*192 + n];
      #pragma unroll
      for (int rg = 0; rg < 4; rg++) {
        int rloc = lg*4 + rg;
        int p = rowbase + wv*16 + rloc;
        bool valid = (p < c0) || (p >= c0p && p < c0p + c1);
        float z = valid ? (acc[nt][rg] + bias) : 0.f;
        if (branch == 0) { s0sum[nt] += z; s0sq[nt] += z*z; }
        else             { s1sum[nt] += z; s1sq[nt] += z*z; }
        myldso[rloc*72 + n] = (f16)z;
      }
    }
    {
      int r2 = lane>>2, q = lane&3;
      int p2 = rowbase + wv*16 + r2;
      f16x8 v0 = *(const f16x8*)(myldso + r2*72 + q*8);
      f16x8 v1 = *(const f16x8*)(myldso + r2*72 + 32 + q*8);
      *(f16x8*)(zout + (size_t)p2*64 + q*8) = v0;
      *(f16x8*)(zout + (size_t)p2*64 + 32 + q*8) = v1;
    }
  }
  #pragma unroll
  for (int nt = 0; nt < 4; nt++) {
    float v, w;
    v = s0sum[nt]; v += __shfl_xor(v,16); v += __shfl_xor(v,32);
    w = s0sq[nt];  w += __shfl_xor(w,16); w += __shfl_xor(w,32);
    if (lane < 16) { atomicAdd(&sstat[0][nt*16+lane][0], v); atomicAdd(&sstat[0][nt*16+lane][1], w); }
    v = s1sum[nt]; v += __shfl_xor(v,16); v += __shfl_xor(v,32);
    w = s1sq[nt];  w += __shfl_xor(w,16); w += __shfl_xor(w,32);
    if (lane < 16) { atomicAdd(&sstat[1][nt*16+lane][0], v); atomicAdd(&sstat[1][nt*16+lane][1], w); }
  }
  __syncthreads();
  {
    float v = ((float*)sstat)[tid];
    if (v != 0.f) atomicAdd(&outstats[(blockIdx.x & (RSTAT-1))*256 + tid], v);
  }
}

// ---------------- final BN + relu + att + sorted segment sum (sequential runs) ----------------
__global__ __launch_bounds__(256) void k_scatter(
    const f16* __restrict__ z3, const float* __restrict__ att,
    const float* __restrict__ bngp, const float* __restrict__ bnbp,
    const float* __restrict__ instats, const int* __restrict__ sc,
    const int* __restrict__ astart,
    float* __restrict__ outt, f16* __restrict__ nfh)
{
  __shared__ float lscale[2][64], lshift[2][64];
  int tid = threadIdx.x;
  int c0 = sc[4];
  {
    int c0p = sc[5], c1 = sc[6];
    (void)c0p; (void)c1;
    if (tid < 128) {
      int b = tid>>6, n = tid&63;
      int cb = b ? sc[6] : sc[4]; if (cb < 1) cb = 1;
      float inv = 1.f/(float)cb;
      int idx = (b*64+n)*2;
      float s = 0.f, sq = 0.f;
      #pragma unroll 8
      for (int r = 0; r < RSTAT; r++) {
        s  += instats[r*256 + idx];
        sq += instats[r*256 + idx + 1];
      }
      float mean = s*inv, var = sq*inv - mean*mean;
      float rstd = rsqrtf(var + EPSF);
      float scl = bngp[b*256+n]*rstd;
      lscale[b][n] = scl;
      lshift[b][n] = bnbp[b*256+n] - mean*scl;
    }
  }
  __syncthreads();
  int gid = blockIdx.x*256 + tid;
  int n = gid >> 3, q = gid & 7;
  if (n >= NN) return;
  int s0 = astart[n];
  int e0 = astart[n+1]; if (e0 > c0) e0 = c0;   // clamp away the alignment gap
  int s1 = astart[NN+n];
  int e1 = astart[NN+n+1];                       // astart[2NN] = c0p+c1
  float a0 = att[0], a1 = att[1];
  float acc[8] = {0,0,0,0,0,0,0,0};
  float scb[8], shb[8];
  // branch 0 run (sequential rows)
  #pragma unroll
  for (int j2 = 0; j2 < 8; j2++) { scb[j2] = lscale[0][q*8+j2]; shb[j2] = lshift[0][q*8+j2]; }
  for (int t = s0; t < e0; t++) {
    f16x8 raw = *(const f16x8*)(z3 + (size_t)t*64 + q*8);
    #pragma unroll
    for (int j2 = 0; j2 < 8; j2++) {
      float x = (float)raw[j2]*scb[j2] + shb[j2];
      acc[j2] += fmaxf(x, 0.f) * a0;   // leaky_relu identity for x>=0
    }
  }
  // branch 1 run
  #pragma unroll
  for (int j2 = 0; j2 < 8; j2++) { scb[j2] = lscale[1][q*8+j2]; shb[j2] = lshift[1][q*8+j2]; }
  for (int t = s1; t < e1; t++) {
    f16x8 raw = *(const f16x8*)(z3 + (size_t)t*64 + q*8);
    #pragma unroll
    for (int j2 = 0; j2 < 8; j2++) {
      float x = (float)raw[j2]*scb[j2] + shb[j2];
      acc[j2] += fmaxf(x, 0.f) * a1;
    }
  }
  float4 lo, hi;
  lo.x=acc[0]; lo.y=acc[1]; lo.z=acc[2]; lo.w=acc[3];
  hi.x=acc[4]; hi.y=acc[5]; hi.z=acc[6]; hi.w=acc[7];
  *(float4*)(outt + (size_t)n*64 + q*8) = lo;
  *(float4*)(outt + (size_t)n*64 + q*8 + 4) = hi;
  f16x8 h;
  #pragma unroll
  for (int j2 = 0; j2 < 8; j2++) h[j2] = (f16)acc[j2];
  *(f16x8*)(nfh + (size_t)n*64 + q*8) = h;
}

extern "C" void kernel_launch(void* const* d_in, const int* in_sizes, int n_in,
                              void* d_out, int out_size, void* d_ws, size_t ws_size,
                              hipStream_t stream)
{
  const float* input_feature = (const float*)d_in[0];
  const float* coords   = (const float*)d_in[1];
  const float* face_x   = (const float*)d_in[3];
  const float* att      = (const float*)d_in[4];
  const float* W_geo    = (const float*)d_in[5];
  const float* b_geo    = (const float*)d_in[6];
  const float* g_geo    = (const float*)d_in[7];
  const float* be_geo   = (const float*)d_in[8];
  const float* spnn_W0  = (const float*)d_in[9];
  const float* spnn_b0  = (const float*)d_in[10];
  const float* spnn_Wr  = (const float*)d_in[11];
  const float* spnn_br  = (const float*)d_in[12];
  const float* bn_g     = (const float*)d_in[13];
  const float* bn_b     = (const float*)d_in[14];
  const int* ewf  = (const int*)d_in[15];
  const int* eidx = (const int*)d_in[16];
  const int* exjk = (const int*)d_in[17];
  const int* exij = (const int*)d_in[18];
  float* out = (float*)d_out;
  char* ws = (char*)d_ws;

  size_t off = 0;
  auto take = [&](size_t bytes) -> char* {
    size_t o = off; off = (off + bytes + 255) & ~(size_t)255; return ws + o;
  };
  const size_t STATBUF = (size_t)RSTAT*256;           // floats per stat buffer
  int*   sc     = (int*)take(256);
  float* stats  = (float*)take(13*STATBUF*sizeof(float));  // geo + 3*4 layer stat buffers, replicated
  int*   cb0    = (int*)take(sizeof(int)*2048);
  int*   cnt    = (int*)take(sizeof(int)*NBIN);
  int*   astart = (int*)take(sizeof(int)*(NBIN+1));
  int*   curn   = (int*)take(sizeof(int)*NBIN);
  int*   btot   = (int*)take(sizeof(int)*512);
  unsigned char* biedge = (unsigned char*)take(E_TRIP);
  int* epos = (int*)take(sizeof(int)*EPAD);
  int* ip   = (int*)take(sizeof(int)*EPAD);
  int* jp   = (int*)take(sizeof(int)*EPAD);
  int* kp   = (int*)take(sizeof(int)*EPAD);
  f16* W0h  = (f16*)take(sizeof(f16)*3*2*64*256);
  f16* Wrh  = (f16*)take(sizeof(f16)*3*2*3*64*64);
  f16* nf16 = (f16*)take(sizeof(f16)*(size_t)NN*64);
  f16* zgeo = (f16*)take(sizeof(f16)*(size_t)EPAD*64);
  f16* zA   = (f16*)take(sizeof(f16)*(size_t)EPAD*64);
  f16* zB   = (f16*)take(sizeof(f16)*(size_t)EPAD*64);
  if (off > ws_size) return;  // workspace insufficient; cannot run

  hipMemsetAsync(sc, 0, 256, stream);
  hipMemsetAsync(stats, 0, 13*STATBUF*sizeof(float), stream);
  hipMemsetAsync(cnt, 0, sizeof(int)*NBIN, stream);

  k_count <<<NBLK, 256, 0, stream>>>(ewf, exij, exjk, biedge, cb0);
  k_scanb <<<1, 1024, 0, stream>>>(cb0, sc);
  k_cvt   <<<6418, 256, 0, stream>>>(spnn_W0, spnn_Wr, input_feature, W0h, Wrh, nf16);
  // counting sort by (branch, i): positions sorted by destination within branch
  k_hist  <<<NBLK, 256, 0, stream>>>(biedge, eidx, cnt);
  k_scan1 <<<391, 512, 0, stream>>>(cnt, astart, btot);
  k_scan2 <<<1, 512, 0, stream>>>(btot);
  k_scan3 <<<391, 512, 0, stream>>>(astart, curn, btot, sc);
  k_place <<<NBLK, 256, 0, stream>>>(biedge, eidx, curn, epos, ip, jp, kp);

  k_geo   <<<NBLK256, 256, 0, stream>>>(coords, face_x, ewf, exij, exjk, W_geo, b_geo,
                                        sc, epos, ip, jp, kp, zgeo, stats);
  for (int t = 0; t < 3; t++) {
    float* outt = out + (size_t)t*NN*64;
    k_layer0<<<1024, 256, 0, stream>>>(nf16, zgeo,
        W0h + (size_t)t*2*64*256, spnn_b0 + t*2*64,
        g_geo, be_geo, stats, stats + (size_t)(1 + t*4)*STATBUF,
        sc, ip, jp, kp, zA);
    f16* zi = zA; f16* zo = zB;
    for (int h = 0; h < 3; h++) {
      k_hidden<<<2048, 256, 0, stream>>>(zi, zo,
          Wrh + (size_t)t*2*3*64*64 + (size_t)h*64*64,
          spnn_br + t*2*3*64 + h*64,
          bn_g + t*2*4*64 + h*64,
          bn_b + t*2*4*64 + h*64,
          stats + (size_t)(1 + t*4 + h)*STATBUF,
          stats + (size_t)(1 + t*4 + h + 1)*STATBUF,
          sc);
      f16* tmp = zi; zi = zo; zo = tmp;
    }
    k_scatter<<<(NN*8 + 255)/256, 256, 0, stream>>>(zi, att,
        bn_g + t*2*4*64 + 3*64, bn_b + t*2*4*64 + 3*64,
        stats + (size_t)(1 + t*4 + 3)*STATBUF, sc, astart, outt, nf16);
  }
}